// Round 10
// baseline (3216.183 us; speedup 1.0000x reference)
//
#include <hip/hip_runtime.h>
#include <hip/hip_bf16.h>
#include <math.h>

#define NTOK 8192     // B*S
#define DMD  2048     // d_model
#define DCC  512      // d_cortical
#define TOKH 4194304  // NTOK*DCC
#define WSZ  262144   // DCC*DCC

typedef __attribute__((ext_vector_type(8))) short short8;
typedef __attribute__((ext_vector_type(4))) float f32x4;

struct R4v { short8 v[4]; };

// ---------------- helpers ---------------------------------------------------
__device__ inline float bf2f(unsigned short u) {
    union { unsigned int i; float f; } x; x.i = ((unsigned int)u) << 16; return x.f;
}
__device__ inline unsigned short f2bf(float f) {
    union { float f; unsigned int i; } x; x.f = f;
    unsigned int u = x.i;
    return (unsigned short)((u + 0x7fffu + ((u >> 16) & 1u)) >> 16);
}

typedef const __attribute__((address_space(1))) unsigned int* gas1_t;
typedef __attribute__((address_space(3))) unsigned int* las3_t;
__device__ inline void async16(const void* g, void* l) {
    __builtin_amdgcn_global_load_lds(
        (gas1_t)g,
        (las3_t)(unsigned int)(unsigned long long)l, 16, 0, 0);
}

// XOR swizzle for [32][512] bf16 LDS tiles (we control write AND read sides)
__device__ inline int csw(int rl, int col) {
    int s = ((rl >> 2) & 3) ^ (rl & 3);
    return rl * 512 + (col ^ (s << 4));
}

// ---------------- fp32 -> bf16 bulk conversion (grid-stride) ----------------
__global__ __launch_bounds__(256)
void cvt_kernel(const float* __restrict__ s, unsigned short* __restrict__ d, int n4)
{
    for (int i = blockIdx.x * 256 + threadIdx.x; i < n4; i += gridDim.x * 256) {
        float4 v = ((const float4*)s)[i];
        ushort4 o;
        o.x = f2bf(v.x); o.y = f2bf(v.y); o.z = f2bf(v.z); o.w = f2bf(v.w);
        ((ushort4*)d)[i] = o;
    }
}

// ---------------- merged fp32 -> bf16 weight conversion ---------------------
struct CvtArgs { const float* src[6]; };

__global__ __launch_bounds__(256)
void wcvt_kernel(CvtArgs ca, unsigned short* __restrict__ dst)
{
    const int total = 1310720;  // f4 units
    for (int i = blockIdx.x * 256 + threadIdx.x; i < total; i += gridDim.x * 256) {
        const float* sp; int base;
        if      (i <  262144) { sp = ca.src[0]; base = 0;       }  // fuse_W
        else if (i <  524288) { sp = ca.src[1]; base = 262144;  }  // up_W
        else if (i <  786432) { sp = ca.src[2]; base = 524288;  }  // lateral_W
        else if (i <  983040) { sp = ca.src[3]; base = 786432;  }  // down_W
        else if (i < 1048576) { sp = ca.src[4]; base = 983040;  }  // out1_W
        else                  { sp = ca.src[5]; base = 1048576; }  // out2_W
        float4 v = ((const float4*)sp)[i - base];
        ushort4 o;
        o.x = f2bf(v.x); o.y = f2bf(v.y); o.z = f2bf(v.z); o.w = f2bf(v.w);
        ((ushort4*)dst)[i] = o;
    }
}

// ---------------- proj_W transpose: (4,512,2048) f32 -> (4,2048,512) bf16 ---
__global__ __launch_bounds__(256)
void ptr_kernel(const float* __restrict__ src, unsigned short* __restrict__ dst)
{
    __shared__ float t[32][33];
    const int o  = blockIdx.z;
    const int jb = blockIdx.x * 32;
    const int kb = blockIdx.y * 32;
    const int r  = threadIdx.x >> 3;
    const int c4 = (threadIdx.x & 7) * 4;
    {
        const float* s = src + ((size_t)o * DCC + kb + r) * DMD + jb + c4;
        float4 v = *(const float4*)s;
        t[r][c4+0]=v.x; t[r][c4+1]=v.y; t[r][c4+2]=v.z; t[r][c4+3]=v.w;
    }
    __syncthreads();
    {
        ushort4 u;
        u.x = f2bf(t[c4+0][r]); u.y = f2bf(t[c4+1][r]);
        u.z = f2bf(t[c4+2][r]); u.w = f2bf(t[c4+3][r]);
        *(ushort4*)(dst + ((size_t)o * DMD + jb + r) * DCC + kb + c4) = u;
    }
}

// ---------------- b' = fuse_b + fuse_W @ proj_b_flat (exact f32) ------------
__global__ __launch_bounds__(256)
void bprime_kernel(const float* __restrict__ fuse_W, const float* __restrict__ fuse_b,
                   const float* __restrict__ proj_b, float* __restrict__ bp)
{
    const int row = blockIdx.x * 8 + (threadIdx.x >> 5);
    const int l32 = threadIdx.x & 31;
    const float* r = fuse_W + (size_t)row * (4 * DCC) + l32 * 64;
    const float* p = proj_b + l32 * 64;
    float s = 0.f;
    #pragma unroll
    for (int k = 0; k < 64; k += 4) {
        float4 v = *(const float4*)(r + k);
        float4 q = *(const float4*)(p + k);
        s += v.x*q.x + v.y*q.y + v.z*q.z + v.w*q.w;
    }
    #pragma unroll
    for (int off = 16; off; off >>= 1) s += __shfl_xor(s, off, 64);
    if (l32 == 0) bp[row] = s + fuse_b[row];
}

// ---------------- batched bf16 MFMA GEMM (m97 structure + XCD swizzle) ------
struct GArgs {
    const unsigned short* A[6];
    const unsigned short* W[6];
    const float*          bias[6];
    const float*          add[6];
    void*                 C[6];
};

template<bool OUTF32, bool GELU>
__global__ __launch_bounds__(256)
void gemm16(GArgs ga, int lda, int ldw, int ldadd, int ldc, int K)
{
    __shared__ unsigned short As[128 * 32];   // 8 KB
    __shared__ unsigned short Bs[128 * 32];   // 8 KB

    const int z    = blockIdx.z;
    const int tid  = threadIdx.x;
    const int wave = tid >> 6;
    const int lane = tid & 63;

    const int nwg   = gridDim.x * gridDim.y;
    const int bid   = blockIdx.y * gridDim.x + blockIdx.x;
    const int swz   = (bid & 7) * (nwg >> 3) + (bid >> 3);
    const int bn    = (swz % gridDim.x) * 128;
    const int bm    = (swz / gridDim.x) * 128;

    const int wr   = wave >> 1;
    const int wc   = wave & 1;

    const unsigned short* Ap = ga.A[z];
    const unsigned short* Wp = ga.W[z];

    const int lrow = lane >> 2;
    const int lcol = (lane & 3) * 8;

    f32x4 acc[4][4] = {};

    for (int k0 = 0; k0 < K; k0 += 32) {
        #pragma unroll
        for (int r = 0; r < 2; ++r) {
            int c = wave + r * 4;
            async16(Ap + (size_t)(bm + c * 16 + lrow) * lda + k0 + lcol, As + c * 512);
            async16(Wp + (size_t)(bn + c * 16 + lrow) * ldw + k0 + lcol, Bs + c * 512);
        }
        __syncthreads();

        short8 af[4], bfr[4];
        #pragma unroll
        for (int i = 0; i < 4; ++i) {
            af[i]  = *(const short8*)&As[(wr * 64 + i * 16 + (lane & 15)) * 32 + (lane >> 4) * 8];
            bfr[i] = *(const short8*)&Bs[(wc * 64 + i * 16 + (lane & 15)) * 32 + (lane >> 4) * 8];
        }
        #pragma unroll
        for (int mi = 0; mi < 4; ++mi)
            #pragma unroll
            for (int ni = 0; ni < 4; ++ni)
                acc[mi][ni] = __builtin_amdgcn_mfma_f32_16x16x32_bf16(
                    af[mi], bfr[ni], acc[mi][ni], 0, 0, 0);
        __syncthreads();
    }

    const float* bias = ga.bias[z];
    const float* add  = ga.add[z];
    #pragma unroll
    for (int ni = 0; ni < 4; ++ni) {
        int col = bn + wc * 64 + ni * 16 + (lane & 15);
        float bv = bias ? bias[col] : 0.0f;
        #pragma unroll
        for (int mi = 0; mi < 4; ++mi) {
            #pragma unroll
            for (int r = 0; r < 4; ++r) {
                int row = bm + wr * 64 + mi * 16 + (lane >> 4) * 4 + r;
                float vv = acc[mi][ni][r] + bv;
                if (GELU) vv = 0.5f * vv * (1.0f + erff(vv * 0.7071067811865475f));
                if (OUTF32) {
                    if (add) vv += add[(size_t)row * ldadd + col];
                    ((float*)ga.C[z])[(size_t)row * ldc + col] = vv;
                } else {
                    ((unsigned short*)ga.C[z])[(size_t)row * ldc + col] = f2bf(vv);
                }
            }
        }
    }
}

// ---------------- x0 reduce: x0 = bf16(sum_o partial_o + b') ----------------
__global__ __launch_bounds__(256)
void x0red(const float* __restrict__ partial, const float* __restrict__ bp,
           unsigned short* __restrict__ x0)
{
    const int i = blockIdx.x * 256 + threadIdx.x;   // f4 units, total 1048576
    float4 a = ((const float4*)partial)[i];
    float4 b = ((const float4*)(partial + TOKH))[i];
    float4 c = ((const float4*)(partial + 2 * (size_t)TOKH))[i];
    float4 d = ((const float4*)(partial + 3 * (size_t)TOKH))[i];
    const int col = (i * 4) & (DCC - 1);
    float4 bv = *(const float4*)(bp + col);
    ushort4 o;
    o.x = f2bf(a.x + b.x + c.x + d.x + bv.x);
    o.y = f2bf(a.y + b.y + c.y + d.y + bv.y);
    o.z = f2bf(a.z + b.z + c.z + d.z + bv.z);
    o.w = f2bf(a.w + b.w + c.w + d.w + bv.w);
    ((ushort4*)x0)[i] = o;
}

// ---------------- persistent mega kernel ------------------------------------
// Grid 256 x 512 threads; block owns tokens bm..bm+31 (token-local algorithm:
// no cross-block deps). acts[0..3] live in registers (R4v: 4 tokens x 8 cols
// per thread, row-mapped). LDS: X 32K (A-staging / output transpose, csw both
// sides) + W dbuf 64K + red 2K = 98 KB -> 1 block/CU, 8 waves.
__global__ __launch_bounds__(512)
void mega_kernel(const unsigned short* __restrict__ x0b,
                 const unsigned short* __restrict__ upW,
                 const float* __restrict__ up_b,
                 const unsigned short* __restrict__ latW,
                 const float* __restrict__ lat_b,
                 const unsigned short* __restrict__ downW,
                 const float* __restrict__ down_b,
                 const unsigned short* __restrict__ out1W,
                 const float* __restrict__ out1_b,
                 const float* __restrict__ ln_g,
                 const float* __restrict__ ln_b,
                 const float* __restrict__ plogit,
                 unsigned short* __restrict__ h16)
{
    __shared__ unsigned short X[32 * 512];      // 32 KB
    __shared__ unsigned short Wb[2][512 * 32];  // 64 KB
    __shared__ float red[2][8][32];             //  2 KB

    const int tid  = threadIdx.x;
    const int wave = tid >> 6;          // 0..7
    const int lane = tid & 63;
    const int lrow = lane >> 2;
    const int lc8  = (lane & 3) * 8;
    const int l15  = lane & 15;
    const int lh   = lane >> 4;
    const int bm   = blockIdx.x * 32;
    const int c0   = lane * 8;

    f32x4 acc[2][4];

    // ---- write A (row-mapped regs) into X, csw layout
    auto writeA = [&](R4v a) {
        __syncthreads();                // prior X readers done
        #pragma unroll
        for (int rr = 0; rr < 4; ++rr)
            *(short8*)&X[csw(wave * 4 + rr, c0)] = a.v[rr];
        __syncthreads();
    };

    // ---- 32x512 GEMM: acc = X(A) @ W^T; W streamed through Wb dbuf
    auto gemmX = [&](const unsigned short* Wp) {
        #pragma unroll
        for (int mi = 0; mi < 2; ++mi)
            #pragma unroll
            for (int ni = 0; ni < 4; ++ni)
                acc[mi][ni] = f32x4{0.f, 0.f, 0.f, 0.f};
        #pragma unroll
        for (int r = 0; r < 4; ++r)
            async16(Wp + (size_t)((r * 8 + wave) * 16 + lrow) * DCC + lc8,
                    &Wb[0][(r * 8 + wave) * 512]);
        __syncthreads();
        for (int t = 0; t < 16; ++t) {
            const int cur = t & 1;
            if (t < 15) {
                const int k0 = (t + 1) * 32;
                #pragma unroll
                for (int r = 0; r < 4; ++r)
                    async16(Wp + (size_t)((r * 8 + wave) * 16 + lrow) * DCC + k0 + lc8,
                            &Wb[cur ^ 1][(r * 8 + wave) * 512]);
            }
            short8 af[2], bfr[4];
            #pragma unroll
            for (int mi = 0; mi < 2; ++mi)
                af[mi] = *(const short8*)&X[csw(mi * 16 + l15, t * 32 + lh * 8)];
            #pragma unroll
            for (int ni = 0; ni < 4; ++ni)
                bfr[ni] = *(const short8*)&Wb[cur][(wave * 64 + ni * 16 + l15) * 32 + lh * 8];
            #pragma unroll
            for (int mi = 0; mi < 2; ++mi)
                #pragma unroll
                for (int ni = 0; ni < 4; ++ni)
                    acc[mi][ni] = __builtin_amdgcn_mfma_f32_16x16x32_bf16(
                        af[mi], bfr[ni], acc[mi][ni], 0, 0, 0);
            __syncthreads();
        }
    };

    // ---- acc (+bias) -> X (MFMA layout -> csw)
    auto accToX = [&](const float* bias) {
        float bv[4];
        #pragma unroll
        for (int ni = 0; ni < 4; ++ni) bv[ni] = bias[wave * 64 + ni * 16 + l15];
        #pragma unroll
        for (int mi = 0; mi < 2; ++mi)
            #pragma unroll
            for (int r2 = 0; r2 < 4; ++r2) {
                int rl = mi * 16 + lh * 4 + r2;
                #pragma unroll
                for (int ni = 0; ni < 4; ++ni) {
                    int col = wave * 64 + ni * 16 + l15;
                    X[csw(rl, col)] = f2bf(acc[mi][ni][r2] + bv[ni]);
                }
            }
        __syncthreads();
    };

    auto readX = [&]() {
        R4v r;
        #pragma unroll
        for (int rr = 0; rr < 4; ++rr)
            r.v[rr] = *(const short8*)&X[csw(wave * 4 + rr, c0)];
        return r;
    };

    // ---- up-GEMM epilogue: comp = LN1(acc + up_b) -> X
    auto compToX = [&](int li) {
        const float* bias = up_b + li * DCC;
        const float* g    = ln_g + li * DCC;
        const float* b    = ln_b + li * DCC;
        float bv[4], gv[4], bbv[4];
        #pragma unroll
        for (int ni = 0; ni < 4; ++ni) {
            int col = wave * 64 + ni * 16 + l15;
            bv[ni] = bias[col]; gv[ni] = g[col]; bbv[ni] = b[col];
        }
        float ps[2][4], pq[2][4];
        #pragma unroll
        for (int mi = 0; mi < 2; ++mi)
            #pragma unroll
            for (int r2 = 0; r2 < 4; ++r2) {
                float s = 0.f, q = 0.f;
                #pragma unroll
                for (int ni = 0; ni < 4; ++ni) {
                    float v = acc[mi][ni][r2] + bv[ni];
                    acc[mi][ni][r2] = v;
                    s += v; q += v * v;
                }
                #pragma unroll
                for (int off = 1; off < 16; off <<= 1) {
                    s += __shfl_xor(s, off, 64);
                    q += __shfl_xor(q, off, 64);
                }
                ps[mi][r2] = s; pq[mi][r2] = q;
            }
        if (l15 == 0) {
            #pragma unroll
            for (int mi = 0; mi < 2; ++mi)
                #pragma unroll
                for (int r2 = 0; r2 < 4; ++r2) {
                    int rl = mi * 16 + lh * 4 + r2;
                    red[0][wave][rl] = ps[mi][r2];
                    red[1][wave][rl] = pq[mi][r2];
                }
        }
        __syncthreads();
        #pragma unroll
        for (int mi = 0; mi < 2; ++mi)
            #pragma unroll
            for (int r2 = 0; r2 < 4; ++r2) {
                int rl = mi * 16 + lh * 4 + r2;
                float s = 0.f, q = 0.f;
                #pragma unroll
                for (int w = 0; w < 8; ++w) { s += red[0][w][rl]; q += red[1][w][rl]; }
                float m1 = s * (1.0f / DCC);
                float r1 = rsqrtf(q * (1.0f / DCC) - m1 * m1 + 1e-5f);
                #pragma unroll
                for (int ni = 0; ni < 4; ++ni) {
                    int col = wave * 64 + ni * 16 + l15;
                    X[csw(rl, col)] = f2bf((acc[mi][ni][r2] - m1) * r1 * gv[ni] + bbv[ni]);
                }
            }
        __syncthreads();
    };

    // ---- settle update: new acts = LN2(a + 0.5*(comp - tgt)*prec + 0.1*lat)
    auto updateL = [&](int li, R4v aIn, R4v tgt, R4v lat) {
        const float* g     = ln_g + li * DCC;
        const float* b     = ln_b + li * DCC;
        const float* logit = plogit + li * DCC;
        float gr[8], br[8], pr[8];
        {
            float4 g0 = *(const float4*)(g + c0),     g1 = *(const float4*)(g + c0 + 4);
            float4 b0 = *(const float4*)(b + c0),     b1 = *(const float4*)(b + c0 + 4);
            float4 p0 = *(const float4*)(logit + c0), p1 = *(const float4*)(logit + c0 + 4);
            float gt[8] = {g0.x,g0.y,g0.z,g0.w,g1.x,g1.y,g1.z,g1.w};
            float bt[8] = {b0.x,b0.y,b0.z,b0.w,b1.x,b1.y,b1.z,b1.w};
            float pt[8] = {p0.x,p0.y,p0.z,p0.w,p1.x,p1.y,p1.z,p1.w};
            #pragma unroll
            for (int j = 0; j < 8; ++j) {
                gr[j] = gt[j]; br[j] = bt[j];
                pr[j] = 1.0f / (1.0f + __expf(-pt[j]));
            }
        }
        R4v outv;
        #pragma unroll
        for (int rr = 0; rr < 4; ++rr) {
            short8 cm = *(const short8*)&X[csw(wave * 4 + rr, c0)];
            float tv[8], s = 0.f, q = 0.f;
            #pragma unroll
            for (int j = 0; j < 8; ++j) {
                float val = bf2f((unsigned short)aIn.v[rr][j])
                          + 0.5f * (bf2f((unsigned short)cm[j]) - bf2f((unsigned short)tgt.v[rr][j])) * pr[j]
                          + 0.1f * bf2f((unsigned short)lat.v[rr][j]);
                tv[j] = val; s += val; q += val * val;
            }
            #pragma unroll
            for (int off = 1; off < 64; off <<= 1) {
                s += __shfl_xor(s, off, 64);
                q += __shfl_xor(q, off, 64);
            }
            float m2 = s * (1.0f / DCC);
            float r2 = rsqrtf(q * (1.0f / DCC) - m2 * m2 + 1e-5f);
            #pragma unroll
            for (int j = 0; j < 8; ++j)
                outv.v[rr][j] = (short)f2bf((tv[j] - m2) * r2 * gr[j] + br[j]);
        }
        return outv;
    };

    // ---- load x0 (row-mapped)
    R4v x0R;
    #pragma unroll
    for (int rr = 0; rr < 4; ++rr)
        x0R.v[rr] = *(const short8*)(x0b + (size_t)(bm + wave * 4 + rr) * DCC + c0);

    R4v actsR[4];

    // ---- bottom-up: acts[i] = LN(A @ upW_i^T + up_b_i)
    #pragma unroll
    for (int i = 0; i < 4; ++i) {
        writeA(i == 0 ? x0R : actsR[i - 1]);
        gemmX(upW + (size_t)i * WSZ);
        compToX(i);
        actsR[i] = readX();
    }

    // ---- settle iterations (all token-local)
    for (int s = 0; s < 5; ++s) {
        // L0: pred_a from acts1 (pre-update), lat0 from acts0, up from x0
        writeA(actsR[1]); gemmX(downW + (size_t)1 * WSZ); accToX(down_b + DCC);
        R4v P = readX();
        writeA(actsR[0]); gemmX(latW); accToX(lat_b);
        R4v Lv = readX();
        writeA(x0R); gemmX(upW); compToX(0);
        actsR[0] = updateL(0, actsR[0], P, Lv);

        // L1: pred_b from acts2 (pre-update), lat1 from acts1, up from new acts0
        writeA(actsR[2]); gemmX(downW + (size_t)2 * WSZ); accToX(down_b + 2 * DCC);
        P = readX();
        writeA(actsR[1]); gemmX(latW + (size_t)1 * WSZ); accToX(lat_b + DCC);
        Lv = readX();
        writeA(actsR[0]); gemmX(upW + (size_t)1 * WSZ); compToX(1);
        actsR[1] = updateL(1, actsR[1], P, Lv);

        // L2: tgt = acts2 (self, pre-update)
        writeA(actsR[2]); gemmX(latW + (size_t)2 * WSZ); accToX(lat_b + 2 * DCC);
        Lv = readX();
        writeA(actsR[1]); gemmX(upW + (size_t)2 * WSZ); compToX(2);
        actsR[2] = updateL(2, actsR[2], actsR[2], Lv);

        // L3: tgt = acts3 (self, pre-update)
        writeA(actsR[3]); gemmX(latW + (size_t)3 * WSZ); accToX(lat_b + 3 * DCC);
        Lv = readX();
        writeA(actsR[2]); gemmX(upW + (size_t)3 * WSZ); compToX(3);
        actsR[3] = updateL(3, actsR[3], actsR[3], Lv);
    }

    // ---- head out1: h = gelu(acts3 @ out1W^T + out1_b) -> global
    writeA(actsR[3]);
    gemmX(out1W);
    {
        float bv[4];
        #pragma unroll
        for (int ni = 0; ni < 4; ++ni) bv[ni] = out1_b[wave * 64 + ni * 16 + l15];
        #pragma unroll
        for (int mi = 0; mi < 2; ++mi)
            #pragma unroll
            for (int r2 = 0; r2 < 4; ++r2) {
                int rl = mi * 16 + lh * 4 + r2;
                #pragma unroll
                for (int ni = 0; ni < 4; ++ni) {
                    int col = wave * 64 + ni * 16 + l15;
                    float vv = acc[mi][ni][r2] + bv[ni];
                    vv = 0.5f * vv * (1.0f + erff(vv * 0.7071067811865475f));
                    h16[(size_t)(bm + rl) * DCC + col] = f2bf(vv);
                }
            }
    }
}

// ---------------------------------------------------------------------------
extern "C" void kernel_launch(void* const* d_in, const int* in_sizes, int n_in,
                              void* d_out, int out_size, void* d_ws, size_t ws_size,
                              hipStream_t stream)
{
    const float* qwen   = (const float*)d_in[0];
    const float* obs    = (const float*)d_in[1];
    const float* proj_W = (const float*)d_in[2];
    const float* proj_b = (const float*)d_in[3];
    const float* fuse_W = (const float*)d_in[4];
    const float* fuse_b = (const float*)d_in[5];
    const float* up_W   = (const float*)d_in[6];
    const float* up_b   = (const float*)d_in[7];
    const float* lat_W  = (const float*)d_in[8];
    const float* lat_b  = (const float*)d_in[9];
    const float* plogit = (const float*)d_in[10];
    const float* ln_g   = (const float*)d_in[11];
    const float* ln_b   = (const float*)d_in[12];
    const float* down_W = (const float*)d_in[13];
    const float* down_b = (const float*)d_in[14];
    const float* out1_W = (const float*)d_in[15];
    const float* out1_b = (const float*)d_in[16];
    const float* out2_W = (const float*)d_in[17];
    const float* out2_b = (const float*)d_in[18];
    float* out = (float*)d_out;

    // ---- ws layout (ushort)
    unsigned short* wsu = (unsigned short*)d_ws;
    float*          bp     = (float*)wsu;                  // 512 f32
    unsigned short* h16    = wsu + 2048;                   // 4.2M ushorts
    unsigned short* M16    = wsu + 8388608;                // (4,512,2048)
    unsigned short* x0b    = wsu + 16777216;               // 4.2M
    unsigned short* w16    = wsu + 37748736;
    unsigned short* fuseW16 = w16;
    unsigned short* upW16   = w16 + 1048576;
    unsigned short* latW16  = w16 + 2097152;
    unsigned short* downW16 = w16 + 3145728;
    unsigned short* out1W16 = w16 + 3932160;
    unsigned short* out2W16 = w16 + 4194304;
    unsigned short* projT16 = wsu + 47185920;              // (4,2048,512)
    unsigned short* obs16   = wsu + 47185920;              // overlays projT16

    // d_out overlays: part32 (front); dead before out2 rewrites out
    float* part32 = (float*)d_out;

    dim3 blk(256);
    dim3 blk512(512);

    {
        CvtArgs ca;
        ca.src[0] = fuse_W; ca.src[1] = up_W;   ca.src[2] = lat_W;
        ca.src[3] = down_W; ca.src[4] = out1_W; ca.src[5] = out2_W;
        wcvt_kernel<<<dim3(2048), blk, 0, stream>>>(ca, w16);
    }
    ptr_kernel<<<dim3(DMD/32, DCC/32, 4), blk, 0, stream>>>(proj_W, projT16);
    bprime_kernel<<<dim3(DCC/8), blk, 0, stream>>>(fuse_W, fuse_b, proj_b, bp);

    // ---- M_o = fuseW_o @ projW_o  (512x2048 each, K=512); consumes projT16
    {
        GArgs a{};
        for (int o = 0; o < 4; ++o) {
            a.A[o] = fuseW16 + o * DCC;
            a.W[o] = projT16 + (size_t)o * DMD * DCC;
            a.bias[o] = nullptr;
            a.C[o] = M16 + (size_t)o * DCC * DMD;
        }
        gemm16<false, false><<<dim3(DMD/128, DCC/128, 4), blk, 0, stream>>>(
            a, 4 * DCC, DCC, 0, DMD, DCC);
    }

    // ---- obs -> bf16 (one BW-bound pass; overwrites dead projT16 region)
    cvt_kernel<<<dim3(4096), blk, 0, stream>>>(obs, obs16, 16777216);

    // ---- x0 split-K partials (z=4, grid 1024) -> f32 part32 in d_out
    {
        GArgs a{};
        for (int o = 0; o < 4; ++o) {
            a.A[o] = obs16 + (size_t)o * NTOK * DMD;
            a.W[o] = M16 + (size_t)o * DCC * DMD;
            a.bias[o] = nullptr;
            a.add[o]  = nullptr;
            a.C[o] = part32 + (size_t)o * TOKH;
        }
        gemm16<true, false><<<dim3(DCC/128, NTOK/128, 4), blk, 0, stream>>>(
            a, DMD, DMD, 0, DCC, DMD);
    }
    x0red<<<dim3(TOKH/4/256), blk, 0, stream>>>(part32, bp, x0b);

    // ---- bottom-up + 5 settle iterations + head-out1: ONE persistent kernel
    mega_kernel<<<dim3(NTOK/32), blk512, 0, stream>>>(
        x0b, upW16, up_b, latW16, lat_b, downW16, down_b,
        out1W16, out1_b, ln_g, ln_b, plogit, h16);

    // ---- head out2: out = qwen + h @ out2W^T + out2_b
    {
        GArgs a{};
        a.A[0] = h16; a.W[0] = out2W16; a.bias[0] = out2_b;
        a.add[0] = qwen; a.C[0] = out;
        gemm16<true, false><<<dim3(DMD/128, NTOK/128, 1), blk, 0, stream>>>(
            a, DCC, DCC, DMD, DMD, DCC);
    }
}

// Round 11
// 1706.902 us; speedup vs baseline: 1.8842x; 1.8842x over previous
//
#include <hip/hip_runtime.h>
#include <hip/hip_bf16.h>
#include <math.h>

#define NTOK 8192     // B*S
#define DMD  2048     // d_model
#define DCC  512      // d_cortical
#define TOKH 4194304  // NTOK*DCC
#define WSZ  262144   // DCC*DCC

typedef __attribute__((ext_vector_type(8))) short short8;
typedef __attribute__((ext_vector_type(4))) float f32x4;

// ---------------- helpers ---------------------------------------------------
__device__ inline float bf2f(unsigned short u) {
    union { unsigned int i; float f; } x; x.i = ((unsigned int)u) << 16; return x.f;
}
__device__ inline unsigned short f2bf(float f) {
    union { float f; unsigned int i; } x; x.f = f;
    unsigned int u = x.i;
    return (unsigned short)((u + 0x7fffu + ((u >> 16) & 1u)) >> 16);
}

typedef const __attribute__((address_space(1))) unsigned int* gas1_t;
typedef __attribute__((address_space(3))) unsigned int* las3_t;
__device__ inline void async16(const void* g, void* l) {
    __builtin_amdgcn_global_load_lds(
        (gas1_t)g,
        (las3_t)(unsigned int)(unsigned long long)l, 16, 0, 0);
}

// XOR swizzle for [32][512] bf16 LDS tiles (we control write AND read sides)
__device__ inline int csw(int rl, int col) {
    int s = ((rl >> 2) & 3) ^ (rl & 3);
    return rl * 512 + (col ^ (s << 4));
}

// ---------------- fp32 -> bf16 bulk conversion (grid-stride) ----------------
__global__ __launch_bounds__(256)
void cvt_kernel(const float* __restrict__ s, unsigned short* __restrict__ d, int n4)
{
    for (int i = blockIdx.x * 256 + threadIdx.x; i < n4; i += gridDim.x * 256) {
        float4 v = ((const float4*)s)[i];
        ushort4 o;
        o.x = f2bf(v.x); o.y = f2bf(v.y); o.z = f2bf(v.z); o.w = f2bf(v.w);
        ((ushort4*)d)[i] = o;
    }
}

// ---------------- merged prep: weight cvt + proj transpose + b' -------------
// blocks 0..2047      : fp32->bf16 weight conversion (grid-stride)
// blocks 2048..6143   : proj_W transpose (4,512,2048) f32 -> (4,2048,512) bf16
// blocks 6144..6207   : b' = fuse_b + fuse_W @ proj_b_flat (exact f32)
struct PrepArgs {
    const float* wsrc[6];        // fuse|up|lat|down|out1|out2
    const float* proj_W;
    const float* fuse_W;
    const float* fuse_b;
    const float* proj_b;
    unsigned short* wdst;        // w16
    unsigned short* projT;       // projT16
    float* bp;
};

__global__ __launch_bounds__(256)
void prep_kernel(PrepArgs pa)
{
    __shared__ float t[32][33];
    const int bid = blockIdx.x;
    const int tid = threadIdx.x;

    if (bid < 2048) {
        const int total = 1310720;  // f4 units
        for (int i = bid * 256 + tid; i < total; i += 2048 * 256) {
            const float* sp; int base;
            if      (i <  262144) { sp = pa.wsrc[0]; base = 0;       }
            else if (i <  524288) { sp = pa.wsrc[1]; base = 262144;  }
            else if (i <  786432) { sp = pa.wsrc[2]; base = 524288;  }
            else if (i <  983040) { sp = pa.wsrc[3]; base = 786432;  }
            else if (i < 1048576) { sp = pa.wsrc[4]; base = 983040;  }
            else                  { sp = pa.wsrc[5]; base = 1048576; }
            float4 v = ((const float4*)sp)[i - base];
            ushort4 o;
            o.x = f2bf(v.x); o.y = f2bf(v.y); o.z = f2bf(v.z); o.w = f2bf(v.w);
            ((ushort4*)pa.wdst)[i] = o;
        }
    } else if (bid < 6144) {
        const int b2  = bid - 2048;            // 0..4095
        const int o   = b2 >> 10;
        const int rem = b2 & 1023;
        const int jb  = (rem & 63) * 32;       // col block in 2048
        const int kb  = (rem >> 6) * 32;       // row block in 512
        const int r   = tid >> 3;
        const int c4  = (tid & 7) * 4;
        {
            const float* s = pa.proj_W + ((size_t)o * DCC + kb + r) * DMD + jb + c4;
            float4 v = *(const float4*)s;
            t[r][c4+0]=v.x; t[r][c4+1]=v.y; t[r][c4+2]=v.z; t[r][c4+3]=v.w;
        }
        __syncthreads();
        {
            ushort4 u;
            u.x = f2bf(t[c4+0][r]); u.y = f2bf(t[c4+1][r]);
            u.z = f2bf(t[c4+2][r]); u.w = f2bf(t[c4+3][r]);
            *(ushort4*)(pa.projT + ((size_t)o * DMD + jb + r) * DCC + kb + c4) = u;
        }
    } else {
        const int b3  = bid - 6144;            // 0..63
        const int row = b3 * 8 + (tid >> 5);
        const int l32 = tid & 31;
        const float* r = pa.fuse_W + (size_t)row * (4 * DCC) + l32 * 64;
        const float* p = pa.proj_b + l32 * 64;
        float s = 0.f;
        #pragma unroll
        for (int k = 0; k < 64; k += 4) {
            float4 v = *(const float4*)(r + k);
            float4 q = *(const float4*)(p + k);
            s += v.x*q.x + v.y*q.y + v.z*q.z + v.w*q.w;
        }
        #pragma unroll
        for (int off = 16; off; off >>= 1) s += __shfl_xor(s, off, 64);
        if (l32 == 0) pa.bp[row] = s + pa.fuse_b[row];
    }
}

// ---------------- batched bf16 MFMA GEMM (m97 structure + XCD swizzle) ------
struct GArgs {
    const unsigned short* A[6];
    const unsigned short* W[6];
    const float*          bias[6];
    const float*          add[6];
    void*                 C[6];
};

template<bool OUTF32, bool GELU>
__global__ __launch_bounds__(256)
void gemm16(GArgs ga, int lda, int ldw, int ldadd, int ldc, int K)
{
    __shared__ unsigned short As[128 * 32];   // 8 KB
    __shared__ unsigned short Bs[128 * 32];   // 8 KB

    const int z    = blockIdx.z;
    const int tid  = threadIdx.x;
    const int wave = tid >> 6;
    const int lane = tid & 63;

    const int nwg   = gridDim.x * gridDim.y;
    const int bid   = blockIdx.y * gridDim.x + blockIdx.x;
    const int swz   = (bid & 7) * (nwg >> 3) + (bid >> 3);
    const int bn    = (swz % gridDim.x) * 128;
    const int bm    = (swz / gridDim.x) * 128;

    const int wr   = wave >> 1;
    const int wc   = wave & 1;

    const unsigned short* Ap = ga.A[z];
    const unsigned short* Wp = ga.W[z];

    const int lrow = lane >> 2;
    const int lcol = (lane & 3) * 8;

    f32x4 acc[4][4] = {};

    for (int k0 = 0; k0 < K; k0 += 32) {
        #pragma unroll
        for (int r = 0; r < 2; ++r) {
            int c = wave + r * 4;
            async16(Ap + (size_t)(bm + c * 16 + lrow) * lda + k0 + lcol, As + c * 512);
            async16(Wp + (size_t)(bn + c * 16 + lrow) * ldw + k0 + lcol, Bs + c * 512);
        }
        __syncthreads();

        short8 af[4], bfr[4];
        #pragma unroll
        for (int i = 0; i < 4; ++i) {
            af[i]  = *(const short8*)&As[(wr * 64 + i * 16 + (lane & 15)) * 32 + (lane >> 4) * 8];
            bfr[i] = *(const short8*)&Bs[(wc * 64 + i * 16 + (lane & 15)) * 32 + (lane >> 4) * 8];
        }
        #pragma unroll
        for (int mi = 0; mi < 4; ++mi)
            #pragma unroll
            for (int ni = 0; ni < 4; ++ni)
                acc[mi][ni] = __builtin_amdgcn_mfma_f32_16x16x32_bf16(
                    af[mi], bfr[ni], acc[mi][ni], 0, 0, 0);
        __syncthreads();
    }

    const float* bias = ga.bias[z];
    const float* add  = ga.add[z];
    #pragma unroll
    for (int ni = 0; ni < 4; ++ni) {
        int col = bn + wc * 64 + ni * 16 + (lane & 15);
        float bv = bias ? bias[col] : 0.0f;
        #pragma unroll
        for (int mi = 0; mi < 4; ++mi) {
            #pragma unroll
            for (int r = 0; r < 4; ++r) {
                int row = bm + wr * 64 + mi * 16 + (lane >> 4) * 4 + r;
                float vv = acc[mi][ni][r] + bv;
                if (GELU) vv = 0.5f * vv * (1.0f + erff(vv * 0.7071067811865475f));
                if (OUTF32) {
                    if (add) vv += add[(size_t)row * ldadd + col];
                    ((float*)ga.C[z])[(size_t)row * ldc + col] = vv;
                } else {
                    ((unsigned short*)ga.C[z])[(size_t)row * ldc + col] = f2bf(vv);
                }
            }
        }
    }
}

// ---------------- x0 reduce: x0 = bf16(sum_o partial_o + b') ----------------
__global__ __launch_bounds__(256)
void x0red(const float* __restrict__ partial, const float* __restrict__ bp,
           unsigned short* __restrict__ x0)
{
    const int i = blockIdx.x * 256 + threadIdx.x;   // f4 units, total 1048576
    float4 a = ((const float4*)partial)[i];
    float4 b = ((const float4*)(partial + TOKH))[i];
    float4 c = ((const float4*)(partial + 2 * (size_t)TOKH))[i];
    float4 d = ((const float4*)(partial + 3 * (size_t)TOKH))[i];
    const int col = (i * 4) & (DCC - 1);
    float4 bv = *(const float4*)(bp + col);
    ushort4 o;
    o.x = f2bf(a.x + b.x + c.x + d.x + bv.x);
    o.y = f2bf(a.y + b.y + c.y + d.y + bv.y);
    o.z = f2bf(a.z + b.z + c.z + d.z + bv.z);
    o.w = f2bf(a.w + b.w + c.w + d.w + bv.w);
    ((ushort4*)x0)[i] = o;
}

// ---------------- fused GEMM + LN (+lat GEMM + update), 8-wave --------------
// Block tile: 32 rows x 512 cols, K=512, 512 threads / 8 waves, grid 256
// (1 block/CU regardless of LDS, so the 32KB latS is occupancy-free).
// MODE 0: out = LN(Ap@Wp^T + bias)
// MODE 1: lat  = a_in@latW^T + lat_bias          (staged to latS; A block-local)
//         comp = LN1(Ap@Wp^T + bias)
//         out  = LN2(a_in + 0.5*(comp - t_in)*sigmoid(logit) + 0.1*lat)
//         (t_in may alias a_in for self-target layers)
// LDS: Bs dbuf 64K + As2 dbuf 4K + latS 32K + red 2K = 102 KB.
template<int MODE>
__global__ __launch_bounds__(512)
void gemm_fused(const unsigned short* __restrict__ Ap,
                const unsigned short* __restrict__ Wp,
                const float* __restrict__ bias,
                const float* __restrict__ g,
                const float* __restrict__ b,
                const unsigned short* a_in,
                const unsigned short* t_in,
                const unsigned short* __restrict__ latW,
                const float* __restrict__ lat_bias,
                const float* __restrict__ logit,
                unsigned short* outp)
{
    __shared__ unsigned short Bs[2][512 * 32];   // 64 KB dbuf
    __shared__ unsigned short As2[2][32 * 32];   //  4 KB dbuf
    __shared__ unsigned short latS[32 * 512];    // 32 KB (MODE 1)
    __shared__ float red[2][8][32];              //  2 KB

    const int tid  = threadIdx.x;
    const int wave = tid >> 6;
    const int lane = tid & 63;
    const int lrow = lane >> 2;
    const int lc8  = (lane & 3) * 8;
    const int bm   = blockIdx.x * 32;
    const int l15  = lane & 15;
    const int lh   = lane >> 4;
    const int c0   = lane * 8;

    f32x4 acc[2][4];

    auto gemmK = [&](const unsigned short* Ag, const unsigned short* Wg) {
        #pragma unroll
        for (int mi = 0; mi < 2; ++mi)
            #pragma unroll
            for (int ni = 0; ni < 4; ++ni)
                acc[mi][ni] = f32x4{0.f, 0.f, 0.f, 0.f};
        if (wave < 2)
            async16(Ag + (size_t)(bm + wave * 16 + lrow) * DCC + lc8, &As2[0][wave * 512]);
        #pragma unroll
        for (int r = 0; r < 4; ++r)
            async16(Wg + (size_t)((r * 8 + wave) * 16 + lrow) * DCC + lc8,
                    &Bs[0][(r * 8 + wave) * 512]);
        __syncthreads();
        for (int t = 0; t < 16; ++t) {
            const int cur = t & 1;
            if (t < 15) {
                const int k0 = (t + 1) * 32;
                if (wave < 2)
                    async16(Ag + (size_t)(bm + wave * 16 + lrow) * DCC + k0 + lc8,
                            &As2[cur ^ 1][wave * 512]);
                #pragma unroll
                for (int r = 0; r < 4; ++r)
                    async16(Wg + (size_t)((r * 8 + wave) * 16 + lrow) * DCC + k0 + lc8,
                            &Bs[cur ^ 1][(r * 8 + wave) * 512]);
            }
            short8 af[2], bfr[4];
            #pragma unroll
            for (int mi = 0; mi < 2; ++mi)
                af[mi] = *(const short8*)&As2[cur][(mi * 16 + l15) * 32 + lh * 8];
            #pragma unroll
            for (int ni = 0; ni < 4; ++ni)
                bfr[ni] = *(const short8*)&Bs[cur][(wave * 64 + ni * 16 + l15) * 32 + lh * 8];
            #pragma unroll
            for (int mi = 0; mi < 2; ++mi)
                #pragma unroll
                for (int ni = 0; ni < 4; ++ni)
                    acc[mi][ni] = __builtin_amdgcn_mfma_f32_16x16x32_bf16(
                        af[mi], bfr[ni], acc[mi][ni], 0, 0, 0);
            __syncthreads();
        }
    };

    // ---- lat GEMM first (A = pre-update acts rows, block-local) -> latS ----
    if constexpr (MODE == 1) {
        gemmK(a_in, latW);
        float lb[4];
        #pragma unroll
        for (int ni = 0; ni < 4; ++ni) lb[ni] = lat_bias[wave * 64 + ni * 16 + l15];
        #pragma unroll
        for (int mi = 0; mi < 2; ++mi)
            #pragma unroll
            for (int r2 = 0; r2 < 4; ++r2) {
                int rl = mi * 16 + lh * 4 + r2;
                #pragma unroll
                for (int ni = 0; ni < 4; ++ni) {
                    int col = wave * 64 + ni * 16 + l15;
                    latS[csw(rl, col)] = f2bf(acc[mi][ni][r2] + lb[ni]);
                }
            }
        // next gemmK's prologue barrier orders latS writes before phase-2 reads
    }

    // ---- up GEMM -----------------------------------------------------------
    gemmK(Ap, Wp);

    // ---- LN1 row stats in MFMA layout --------------------------------------
    float bv[4], gv[4], bbv[4];
    #pragma unroll
    for (int ni = 0; ni < 4; ++ni) {
        int col = wave * 64 + ni * 16 + l15;
        bv[ni] = bias[col]; gv[ni] = g[col]; bbv[ni] = b[col];
    }

    float ps[2][4], pq[2][4];
    #pragma unroll
    for (int mi = 0; mi < 2; ++mi)
        #pragma unroll
        for (int rr = 0; rr < 4; ++rr) {
            float s = 0.f, q = 0.f;
            #pragma unroll
            for (int ni = 0; ni < 4; ++ni) {
                float v = acc[mi][ni][rr] + bv[ni];
                acc[mi][ni][rr] = v;
                s += v; q += v * v;
            }
            #pragma unroll
            for (int off = 1; off < 16; off <<= 1) {
                s += __shfl_xor(s, off, 64);
                q += __shfl_xor(q, off, 64);
            }
            ps[mi][rr] = s; pq[mi][rr] = q;
        }
    if (l15 == 0) {
        #pragma unroll
        for (int mi = 0; mi < 2; ++mi)
            #pragma unroll
            for (int rr = 0; rr < 4; ++rr) {
                int rl = mi * 16 + lh * 4 + rr;
                red[0][wave][rl] = ps[mi][rr];
                red[1][wave][rl] = pq[mi][rr];
            }
    }
    __syncthreads();

    // comp = LN1 result -> compS (reuse Bs[0]; K-loop's last reads were Bs[1])
    unsigned short* compS = &Bs[0][0];
    #pragma unroll
    for (int mi = 0; mi < 2; ++mi)
        #pragma unroll
        for (int rr = 0; rr < 4; ++rr) {
            int rl = mi * 16 + lh * 4 + rr;
            float s = 0.f, q = 0.f;
            #pragma unroll
            for (int w = 0; w < 8; ++w) { s += red[0][w][rl]; q += red[1][w][rl]; }
            float m1 = s * (1.0f / DCC);
            float r1 = rsqrtf(q * (1.0f / DCC) - m1 * m1 + 1e-5f);
            #pragma unroll
            for (int ni = 0; ni < 4; ++ni) {
                int col = wave * 64 + ni * 16 + l15;
                compS[csw(rl, col)] = f2bf((acc[mi][ni][rr] - m1) * r1 * gv[ni] + bbv[ni]);
            }
        }
    __syncthreads();

    // ---- phase 2: row-mapped (wave owns 4 rows, lane owns 8 contiguous cols)
    if constexpr (MODE == 0) {
        #pragma unroll
        for (int rr = 0; rr < 4; ++rr) {
            const int rl = wave * 4 + rr;
            const size_t gbase = (size_t)(bm + rl) * DCC + c0;
            short8 cm = *(const short8*)&compS[csw(rl, c0)];
            *(short8*)(outp + gbase) = cm;
        }
    } else {
        float gr[8], br[8], pr[8];
        {
            float4 g0 = *(const float4*)(g + c0),     g1 = *(const float4*)(g + c0 + 4);
            float4 b0 = *(const float4*)(b + c0),     b1 = *(const float4*)(b + c0 + 4);
            float4 p0 = *(const float4*)(logit + c0), p1 = *(const float4*)(logit + c0 + 4);
            float gt[8] = {g0.x,g0.y,g0.z,g0.w,g1.x,g1.y,g1.z,g1.w};
            float bt[8] = {b0.x,b0.y,b0.z,b0.w,b1.x,b1.y,b1.z,b1.w};
            float pt[8] = {p0.x,p0.y,p0.z,p0.w,p1.x,p1.y,p1.z,p1.w};
            #pragma unroll
            for (int j = 0; j < 8; ++j) {
                gr[j] = gt[j]; br[j] = bt[j];
                pr[j] = 1.0f / (1.0f + __expf(-pt[j]));
            }
        }
        #pragma unroll
        for (int rr = 0; rr < 4; ++rr) {
            const int rl = wave * 4 + rr;
            const size_t gbase = (size_t)(bm + rl) * DCC + c0;
            short8 cm = *(const short8*)&compS[csw(rl, c0)];
            short8 lm = *(const short8*)&latS[csw(rl, c0)];
            short8 ar = *(const short8*)(a_in + gbase);
            short8 tr = *(const short8*)(t_in + gbase);
            float tv[8], s = 0.f, q = 0.f;
            #pragma unroll
            for (int j = 0; j < 8; ++j) {
                float val = bf2f((unsigned short)ar[j])
                          + 0.5f * (bf2f((unsigned short)cm[j]) - bf2f((unsigned short)tr[j])) * pr[j]
                          + 0.1f * bf2f((unsigned short)lm[j]);
                tv[j] = val; s += val; q += val * val;
            }
            #pragma unroll
            for (int off = 1; off < 64; off <<= 1) {
                s += __shfl_xor(s, off, 64);
                q += __shfl_xor(q, off, 64);
            }
            float m2 = s * (1.0f / DCC);
            float r2 = rsqrtf(q * (1.0f / DCC) - m2 * m2 + 1e-5f);
            short8 o;
            #pragma unroll
            for (int j = 0; j < 8; ++j)
                o[j] = (short)f2bf((tv[j] - m2) * r2 * gr[j] + br[j]);
            *(short8*)(outp + gbase) = o;
        }
    }
}

// ---------------------------------------------------------------------------
extern "C" void kernel_launch(void* const* d_in, const int* in_sizes, int n_in,
                              void* d_out, int out_size, void* d_ws, size_t ws_size,
                              hipStream_t stream)
{
    const float* qwen   = (const float*)d_in[0];
    const float* obs    = (const float*)d_in[1];
    const float* proj_W = (const float*)d_in[2];
    const float* proj_b = (const float*)d_in[3];
    const float* fuse_W = (const float*)d_in[4];
    const float* fuse_b = (const float*)d_in[5];
    const float* up_W   = (const float*)d_in[6];
    const float* up_b   = (const float*)d_in[7];
    const float* lat_W  = (const float*)d_in[8];
    const float* lat_b  = (const float*)d_in[9];
    const float* plogit = (const float*)d_in[10];
    const float* ln_g   = (const float*)d_in[11];
    const float* ln_b   = (const float*)d_in[12];
    const float* down_W = (const float*)d_in[13];
    const float* down_b = (const float*)d_in[14];
    const float* out1_W = (const float*)d_in[15];
    const float* out1_b = (const float*)d_in[16];
    const float* out2_W = (const float*)d_in[17];
    const float* out2_b = (const float*)d_in[18];
    float* out = (float*)d_out;

    // ---- ws layout (ushort); footprint 228.6 MB (proven)
    unsigned short* wsu = (unsigned short*)d_ws;
    float*          bp     = (float*)wsu;                  // 512 f32
    unsigned short* h16    = wsu + 2048;                   // head scratch
    unsigned short* M16    = wsu + 8388608;                // (4,512,2048)
    unsigned short* x0b    = wsu + 16777216;
    unsigned short* acts16[4] = {
        wsu + 20971520, wsu + 20971520 + TOKH,
        wsu + 20971520 + 2 * TOKH, wsu + 20971520 + 3 * TOKH };
    unsigned short* w16    = wsu + 37748736;
    unsigned short* fuseW16 = w16;
    unsigned short* upW16   = w16 + 1048576;
    unsigned short* latW16  = w16 + 2097152;
    unsigned short* downW16 = w16 + 3145728;
    unsigned short* out1W16 = w16 + 3932160;
    unsigned short* out2W16 = w16 + 4194304;
    unsigned short* projT16 = wsu + 47185920;              // (4,2048,512)
    unsigned short* obs16   = wsu + 47185920;              // overlays projT16

    // d_out overlays: part32 (front phase); pred a/b (settle); dead before out2
    float*          part32  = (float*)d_out;
    unsigned short* outu = (unsigned short*)d_out;
    unsigned short* pred16a = outu;
    unsigned short* pred16b = outu + TOKH;

    dim3 blk(256);
    dim3 blk512(512);

    // ---- prep: weight cvt + proj transpose + b' in one launch
    {
        PrepArgs pa;
        pa.wsrc[0] = fuse_W; pa.wsrc[1] = up_W;   pa.wsrc[2] = lat_W;
        pa.wsrc[3] = down_W; pa.wsrc[4] = out1_W; pa.wsrc[5] = out2_W;
        pa.proj_W = proj_W; pa.fuse_W = fuse_W; pa.fuse_b = fuse_b;
        pa.proj_b = proj_b;
        pa.wdst = w16; pa.projT = projT16; pa.bp = bp;
        prep_kernel<<<dim3(6208), blk, 0, stream>>>(pa);
    }

    // ---- M_o = fuseW_o @ projW_o  (512x2048 each, K=512); consumes projT16
    {
        GArgs a{};
        for (int o = 0; o < 4; ++o) {
            a.A[o] = fuseW16 + o * DCC;
            a.W[o] = projT16 + (size_t)o * DMD * DCC;
            a.bias[o] = nullptr;
            a.C[o] = M16 + (size_t)o * DCC * DMD;
        }
        gemm16<false, false><<<dim3(DMD/128, DCC/128, 4), blk, 0, stream>>>(
            a, 4 * DCC, DCC, 0, DMD, DCC);
    }

    // ---- obs -> bf16 (one BW-bound pass; overwrites dead projT16 region)
    cvt_kernel<<<dim3(4096), blk, 0, stream>>>(obs, obs16, 16777216);

    // ---- x0 split-K partials: pure-bf16 gemm16, grid 1024 = ~4 blocks/CU
    {
        GArgs a{};
        for (int o = 0; o < 4; ++o) {
            a.A[o] = obs16 + (size_t)o * NTOK * DMD;
            a.W[o] = M16 + (size_t)o * DCC * DMD;
            a.bias[o] = nullptr;
            a.add[o]  = nullptr;
            a.C[o] = part32 + (size_t)o * TOKH;
        }
        gemm16<true, false><<<dim3(DCC/128, NTOK/128, 4), blk, 0, stream>>>(
            a, DMD, DMD, 0, DCC, DMD);
    }
    // ---- x0 = bf16(sum partials + b')
    x0red<<<dim3(TOKH/4/256), blk, 0, stream>>>(part32, bp, x0b);

    dim3 fgrid(NTOK / 32);

    // ---- initial bottom-up pass
    for (int i = 0; i < 4; ++i) {
        gemm_fused<0><<<fgrid, blk512, 0, stream>>>(
            (i == 0) ? x0b : acts16[i - 1],
            upW16 + (size_t)i * DCC * DCC, up_b + i * DCC,
            ln_g + i * DCC, ln_b + i * DCC,
            nullptr, nullptr, nullptr, nullptr, nullptr, acts16[i]);
    }

    // ---- settling iterations: z2 pred batch + 4 fused (lat GEMM inlined)
    for (int s = 0; s < 5; ++s) {
        {
            GArgs a{};
            a.A[0] = acts16[1]; a.W[0] = downW16 + (size_t)1 * DCC * DCC;
            a.bias[0] = down_b + 1 * DCC; a.C[0] = pred16a;
            a.A[1] = acts16[2]; a.W[1] = downW16 + (size_t)2 * DCC * DCC;
            a.bias[1] = down_b + 2 * DCC; a.C[1] = pred16b;
            gemm16<false, false><<<dim3(DCC/128, NTOK/128, 2), blk, 0, stream>>>(
                a, DCC, DCC, 0, DCC, DCC);
        }
        for (int i = 0; i < 4; ++i) {
            const unsigned short* tgt =
                (i == 0) ? pred16a : (i == 1) ? pred16b : acts16[i];
            gemm_fused<1><<<fgrid, blk512, 0, stream>>>(
                (i == 0) ? x0b : acts16[i - 1],
                upW16 + (size_t)i * DCC * DCC, up_b + i * DCC,
                ln_g + i * DCC, ln_b + i * DCC,
                acts16[i], tgt,
                latW16 + (size_t)i * DCC * DCC, lat_b + i * DCC,
                plogit + i * DCC, acts16[i]);
        }
    }

    // ---- head
    {
        GArgs a{};
        a.A[0] = acts16[3]; a.W[0] = out1W16; a.bias[0] = out1_b; a.C[0] = h16;
        gemm16<false, true><<<dim3(DCC/128, NTOK/128, 1), blk, 0, stream>>>(
            a, DCC, DCC, 0, DCC, DCC);
    }
    {
        GArgs a{};
        a.A[0] = h16; a.W[0] = out2W16; a.bias[0] = out2_b;
        a.add[0] = qwen; a.C[0] = out;
        gemm16<true, false><<<dim3(DMD/128, NTOK/128, 1), blk, 0, stream>>>(
            a, DCC, DCC, DMD, DMD, DCC);
    }
}

// Round 12
// 1610.422 us; speedup vs baseline: 1.9971x; 1.0599x over previous
//
#include <hip/hip_runtime.h>
#include <hip/hip_bf16.h>
#include <math.h>

#define NTOK 8192     // B*S
#define DMD  2048     // d_model
#define DCC  512      // d_cortical
#define TOKH 4194304  // NTOK*DCC

typedef __attribute__((ext_vector_type(8))) short short8;
typedef __attribute__((ext_vector_type(4))) float f32x4;

// ---------------- helpers ---------------------------------------------------
__device__ inline float bf2f(unsigned short u) {
    union { unsigned int i; float f; } x; x.i = ((unsigned int)u) << 16; return x.f;
}
__device__ inline unsigned short f2bf(float f) {
    union { float f; unsigned int i; } x; x.f = f;
    unsigned int u = x.i;
    return (unsigned short)((u + 0x7fffu + ((u >> 16) & 1u)) >> 16);
}

typedef const __attribute__((address_space(1))) unsigned int* gas1_t;
typedef __attribute__((address_space(3))) unsigned int* las3_t;
__device__ inline void async16(const void* g, void* l) {
    __builtin_amdgcn_global_load_lds(
        (gas1_t)g,
        (las3_t)(unsigned int)(unsigned long long)l, 16, 0, 0);
}

// ---------------- fp32 -> bf16 bulk conversion (grid-stride) ----------------
__global__ __launch_bounds__(256)
void cvt_kernel(const float* __restrict__ s, unsigned short* __restrict__ d, int n4)
{
    for (int i = blockIdx.x * 256 + threadIdx.x; i < n4; i += gridDim.x * 256) {
        float4 v = ((const float4*)s)[i];
        ushort4 o;
        o.x = f2bf(v.x); o.y = f2bf(v.y); o.z = f2bf(v.z); o.w = f2bf(v.w);
        ((ushort4*)d)[i] = o;
    }
}

// ---------------- merged fp32 -> bf16 weight conversion ---------------------
struct CvtArgs { const float* src[6]; };

__global__ __launch_bounds__(256)
void wcvt_kernel(CvtArgs ca, unsigned short* __restrict__ dst)
{
    const int total = 1310720;  // f4 units
    for (int i = blockIdx.x * 256 + threadIdx.x; i < total; i += gridDim.x * 256) {
        const float* sp; int base;
        if      (i <  262144) { sp = ca.src[0]; base = 0;       }  // fuse_W
        else if (i <  524288) { sp = ca.src[1]; base = 262144;  }  // up_W
        else if (i <  786432) { sp = ca.src[2]; base = 524288;  }  // lateral_W
        else if (i <  983040) { sp = ca.src[3]; base = 786432;  }  // down_W
        else if (i < 1048576) { sp = ca.src[4]; base = 983040;  }  // out1_W
        else                  { sp = ca.src[5]; base = 1048576; }  // out2_W
        float4 v = ((const float4*)sp)[i - base];
        ushort4 o;
        o.x = f2bf(v.x); o.y = f2bf(v.y); o.z = f2bf(v.z); o.w = f2bf(v.w);
        ((ushort4*)dst)[i] = o;
    }
}

// ---------------- proj_W transpose: (4,512,2048) f32 -> (4,2048,512) bf16 ---
__global__ __launch_bounds__(256)
void ptr_kernel(const float* __restrict__ src, unsigned short* __restrict__ dst)
{
    __shared__ float t[32][33];
    const int o  = blockIdx.z;
    const int jb = blockIdx.x * 32;
    const int kb = blockIdx.y * 32;
    const int r  = threadIdx.x >> 3;
    const int c4 = (threadIdx.x & 7) * 4;
    {
        const float* s = src + ((size_t)o * DCC + kb + r) * DMD + jb + c4;
        float4 v = *(const float4*)s;
        t[r][c4+0]=v.x; t[r][c4+1]=v.y; t[r][c4+2]=v.z; t[r][c4+3]=v.w;
    }
    __syncthreads();
    {
        ushort4 u;
        u.x = f2bf(t[c4+0][r]); u.y = f2bf(t[c4+1][r]);
        u.z = f2bf(t[c4+2][r]); u.w = f2bf(t[c4+3][r]);
        *(ushort4*)(dst + ((size_t)o * DMD + jb + r) * DCC + kb + c4) = u;
    }
}

// ---------------- b' = fuse_b + fuse_W @ proj_b_flat (exact f32) ------------
__global__ __launch_bounds__(256)
void bprime_kernel(const float* __restrict__ fuse_W, const float* __restrict__ fuse_b,
                   const float* __restrict__ proj_b, float* __restrict__ bp)
{
    const int row = blockIdx.x * 8 + (threadIdx.x >> 5);
    const int l32 = threadIdx.x & 31;
    const float* r = fuse_W + (size_t)row * (4 * DCC) + l32 * 64;
    const float* p = proj_b + l32 * 64;
    float s = 0.f;
    #pragma unroll
    for (int k = 0; k < 64; k += 4) {
        float4 v = *(const float4*)(r + k);
        float4 q = *(const float4*)(p + k);
        s += v.x*q.x + v.y*q.y + v.z*q.z + v.w*q.w;
    }
    #pragma unroll
    for (int off = 16; off; off >>= 1) s += __shfl_xor(s, off, 64);
    if (l32 == 0) bp[row] = s + fuse_b[row];
}

// ---------------- batched bf16 MFMA GEMM (m97 structure + XCD swizzle) ------
struct GArgs {
    const unsigned short* A[6];
    const unsigned short* W[6];
    const float*          bias[6];
    const float*          add[6];
    void*                 C[6];
};

template<bool OUTF32, bool GELU>
__global__ __launch_bounds__(256)
void gemm16(GArgs ga, int lda, int ldw, int ldadd, int ldc, int K)
{
    __shared__ unsigned short As[128 * 32];   // 8 KB
    __shared__ unsigned short Bs[128 * 32];   // 8 KB

    const int z    = blockIdx.z;
    const int tid  = threadIdx.x;
    const int wave = tid >> 6;
    const int lane = tid & 63;

    const int nwg   = gridDim.x * gridDim.y;
    const int bid   = blockIdx.y * gridDim.x + blockIdx.x;
    const int swz   = (bid & 7) * (nwg >> 3) + (bid >> 3);
    const int bn    = (swz % gridDim.x) * 128;
    const int bm    = (swz / gridDim.x) * 128;

    const int wr   = wave >> 1;
    const int wc   = wave & 1;

    const unsigned short* Ap = ga.A[z];
    const unsigned short* Wp = ga.W[z];

    const int lrow = lane >> 2;
    const int lcol = (lane & 3) * 8;

    f32x4 acc[4][4] = {};

    for (int k0 = 0; k0 < K; k0 += 32) {
        #pragma unroll
        for (int r = 0; r < 2; ++r) {
            int c = wave + r * 4;
            async16(Ap + (size_t)(bm + c * 16 + lrow) * lda + k0 + lcol, As + c * 512);
            async16(Wp + (size_t)(bn + c * 16 + lrow) * ldw + k0 + lcol, Bs + c * 512);
        }
        __syncthreads();

        short8 af[4], bfr[4];
        #pragma unroll
        for (int i = 0; i < 4; ++i) {
            af[i]  = *(const short8*)&As[(wr * 64 + i * 16 + (lane & 15)) * 32 + (lane >> 4) * 8];
            bfr[i] = *(const short8*)&Bs[(wc * 64 + i * 16 + (lane & 15)) * 32 + (lane >> 4) * 8];
        }
        #pragma unroll
        for (int mi = 0; mi < 4; ++mi)
            #pragma unroll
            for (int ni = 0; ni < 4; ++ni)
                acc[mi][ni] = __builtin_amdgcn_mfma_f32_16x16x32_bf16(
                    af[mi], bfr[ni], acc[mi][ni], 0, 0, 0);
        __syncthreads();
    }

    const float* bias = ga.bias[z];
    const float* add  = ga.add[z];
    #pragma unroll
    for (int ni = 0; ni < 4; ++ni) {
        int col = bn + wc * 64 + ni * 16 + (lane & 15);
        float bv = bias ? bias[col] : 0.0f;
        #pragma unroll
        for (int mi = 0; mi < 4; ++mi) {
            #pragma unroll
            for (int r = 0; r < 4; ++r) {
                int row = bm + wr * 64 + mi * 16 + (lane >> 4) * 4 + r;
                float vv = acc[mi][ni][r] + bv;
                if (GELU) vv = 0.5f * vv * (1.0f + erff(vv * 0.7071067811865475f));
                if (OUTF32) {
                    if (add) vv += add[(size_t)row * ldadd + col];
                    ((float*)ga.C[z])[(size_t)row * ldc + col] = vv;
                } else {
                    ((unsigned short*)ga.C[z])[(size_t)row * ldc + col] = f2bf(vv);
                }
            }
        }
    }
}

// ---------------- x0 reduce: x0 = bf16(sum_o partial_o + b') ----------------
__global__ __launch_bounds__(256)
void x0red(const float* __restrict__ partial, const float* __restrict__ bp,
           unsigned short* __restrict__ x0)
{
    const int i = blockIdx.x * 256 + threadIdx.x;   // f4 units, total 1048576
    float4 a = ((const float4*)partial)[i];
    float4 b = ((const float4*)(partial + TOKH))[i];
    float4 c = ((const float4*)(partial + 2 * (size_t)TOKH))[i];
    float4 d = ((const float4*)(partial + 3 * (size_t)TOKH))[i];
    const int col = (i * 4) & (DCC - 1);
    float4 bv = *(const float4*)(bp + col);
    ushort4 o;
    o.x = f2bf(a.x + b.x + c.x + d.x + bv.x);
    o.y = f2bf(a.y + b.y + c.y + d.y + bv.y);
    o.z = f2bf(a.z + b.z + c.z + d.z + bv.z);
    o.w = f2bf(a.w + b.w + c.w + d.w + bv.w);
    ((ushort4*)x0)[i] = o;
}

// ---------------- fused GEMM + LN (+update), 16-row / 2 blocks per CU -------
// Block tile: 16 rows x 512 cols, K=512, 512 threads / 8 waves, grid 512.
// LDS: Bs dbuf 64K + As2 dbuf 2K + red 1K = 67 KB -> 2 blocks/CU: the
// co-resident block hides the K-loop barrier/waitcnt stalls (grid was the
// occupancy limiter at 32-row tiles, not LDS).
// MODE 0: out = LN(A@W^T + bias)
// MODE 1: comp = LN1(A@W^T + bias);
//         out  = LN2(a_in + 0.5*(comp - tgt)*sigmoid(logit) + 0.1*lat)
__device__ inline int csw(int rl, int col) {
    int s = ((rl >> 2) & 3) ^ (rl & 3);
    return rl * 512 + (col ^ (s << 4));
}

template<int MODE>
__global__ __launch_bounds__(512)
void gemm_fused(const unsigned short* __restrict__ Ap,
                const unsigned short* __restrict__ Wp,
                const float* __restrict__ bias,
                const float* __restrict__ g,
                const float* __restrict__ b,
                const unsigned short* a_in,
                const unsigned short* t_in,
                const unsigned short* __restrict__ lat_in,
                const float* __restrict__ logit,
                unsigned short* outp)
{
    __shared__ unsigned short Bs[2][512 * 32];   // 64 KB dbuf
    __shared__ unsigned short As2[2][16 * 32];   //  2 KB dbuf
    __shared__ float red[2][8][16];              //  1 KB

    const int tid  = threadIdx.x;
    const int wave = tid >> 6;         // 0..7
    const int lane = tid & 63;
    const int lrow = lane >> 2;        // 0..15
    const int lc8  = (lane & 3) * 8;   // 0,8,16,24
    const int bm   = blockIdx.x * 16;
    const int l15  = lane & 15;
    const int lh   = lane >> 4;
    const int c0   = lane * 8;

    f32x4 acc[4] = {};

    // prologue stage buf0, k=0 (wave 0 stages the whole 16x32 A tile)
    if (wave == 0)
        async16(Ap + (size_t)(bm + lrow) * DCC + lc8, &As2[0][0]);
    #pragma unroll
    for (int r = 0; r < 4; ++r)
        async16(Wp + (size_t)((r * 8 + wave) * 16 + lrow) * DCC + lc8,
                &Bs[0][(r * 8 + wave) * 512]);
    __syncthreads();   // drains vmcnt(0) -> buf0 ready

    for (int t = 0; t < 16; ++t) {
        const int cur = t & 1;
        if (t < 15) {  // prefetch next K-tile into other buffer
            const int k0 = (t + 1) * 32;
            if (wave == 0)
                async16(Ap + (size_t)(bm + lrow) * DCC + k0 + lc8, &As2[cur ^ 1][0]);
            #pragma unroll
            for (int r = 0; r < 4; ++r)
                async16(Wp + (size_t)((r * 8 + wave) * 16 + lrow) * DCC + k0 + lc8,
                        &Bs[cur ^ 1][(r * 8 + wave) * 512]);
        }
        short8 af = *(const short8*)&As2[cur][l15 * 32 + lh * 8];
        #pragma unroll
        for (int ni = 0; ni < 4; ++ni) {
            short8 bfr = *(const short8*)&Bs[cur][(wave * 64 + ni * 16 + l15) * 32 + lh * 8];
            acc[ni] = __builtin_amdgcn_mfma_f32_16x16x32_bf16(af, bfr, acc[ni], 0, 0, 0);
        }
        __syncthreads();   // next-tile vmcnt drained + this-tile lgkm
    }

    // ---- LN1 row stats in MFMA layout ----
    float bv[4], gv[4], bbv[4];
    #pragma unroll
    for (int ni = 0; ni < 4; ++ni) {
        int col = wave * 64 + ni * 16 + l15;
        bv[ni] = bias[col]; gv[ni] = g[col]; bbv[ni] = b[col];
    }

    float ps[4], pq[4];
    #pragma unroll
    for (int rr = 0; rr < 4; ++rr) {
        float s = 0.f, q = 0.f;
        #pragma unroll
        for (int ni = 0; ni < 4; ++ni) {
            float v = acc[ni][rr] + bv[ni];
            acc[ni][rr] = v;
            s += v; q += v * v;
        }
        #pragma unroll
        for (int off = 1; off < 16; off <<= 1) {
            s += __shfl_xor(s, off, 64);
            q += __shfl_xor(q, off, 64);
        }
        ps[rr] = s; pq[rr] = q;
    }
    if (l15 == 0) {
        #pragma unroll
        for (int rr = 0; rr < 4; ++rr) {
            int rl = lh * 4 + rr;
            red[0][wave][rl] = ps[rr];
            red[1][wave][rl] = pq[rr];
        }
    }
    __syncthreads();

    // comp = LN1 result, staged to LDS (reuse Bs[0]: 16x512 bf16 = 16 KB;
    // K-loop's final reads were from Bs[1], so Bs[0] is dead here)
    unsigned short* compS = &Bs[0][0];
    #pragma unroll
    for (int rr = 0; rr < 4; ++rr) {
        int rl = lh * 4 + rr;
        float s = 0.f, q = 0.f;
        #pragma unroll
        for (int w = 0; w < 8; ++w) { s += red[0][w][rl]; q += red[1][w][rl]; }
        float m1 = s * (1.0f / DCC);
        float r1 = rsqrtf(q * (1.0f / DCC) - m1 * m1 + 1e-5f);
        #pragma unroll
        for (int ni = 0; ni < 4; ++ni) {
            int col = wave * 64 + ni * 16 + l15;
            compS[csw(rl, col)] = f2bf((acc[ni][rr] - m1) * r1 * gv[ni] + bbv[ni]);
        }
    }
    __syncthreads();

    // ---- phase 2: row-mapped (wave owns 2 rows, lane owns 8 contiguous cols)
    if constexpr (MODE == 0) {
        #pragma unroll
        for (int rr = 0; rr < 2; ++rr) {
            const int rl = wave * 2 + rr;
            const size_t gbase = (size_t)(bm + rl) * DCC + c0;
            short8 cm = *(const short8*)&compS[csw(rl, c0)];
            *(short8*)(outp + gbase) = cm;
        }
    } else {
        float gr[8], br[8], pr[8];
        {
            float4 g0 = *(const float4*)(g + c0),     g1 = *(const float4*)(g + c0 + 4);
            float4 b0 = *(const float4*)(b + c0),     b1 = *(const float4*)(b + c0 + 4);
            float4 p0 = *(const float4*)(logit + c0), p1 = *(const float4*)(logit + c0 + 4);
            float gt[8] = {g0.x,g0.y,g0.z,g0.w,g1.x,g1.y,g1.z,g1.w};
            float bt[8] = {b0.x,b0.y,b0.z,b0.w,b1.x,b1.y,b1.z,b1.w};
            float pt[8] = {p0.x,p0.y,p0.z,p0.w,p1.x,p1.y,p1.z,p1.w};
            #pragma unroll
            for (int j = 0; j < 8; ++j) {
                gr[j] = gt[j]; br[j] = bt[j];
                pr[j] = 1.0f / (1.0f + __expf(-pt[j]));
            }
        }
        #pragma unroll
        for (int rr = 0; rr < 2; ++rr) {
            const int rl = wave * 2 + rr;
            const size_t gbase = (size_t)(bm + rl) * DCC + c0;
            short8 cm = *(const short8*)&compS[csw(rl, c0)];
            short8 ar = *(const short8*)(a_in + gbase);
            short8 tr = *(const short8*)(t_in + gbase);
            short8 lr = *(const short8*)(lat_in + gbase);
            float tv[8], s = 0.f, q = 0.f;
            #pragma unroll
            for (int j = 0; j < 8; ++j) {
                float val = bf2f((unsigned short)ar[j])
                          + 0.5f * (bf2f((unsigned short)cm[j]) - bf2f((unsigned short)tr[j])) * pr[j]
                          + 0.1f * bf2f((unsigned short)lr[j]);
                tv[j] = val; s += val; q += val * val;
            }
            #pragma unroll
            for (int off = 1; off < 64; off <<= 1) {
                s += __shfl_xor(s, off, 64);
                q += __shfl_xor(q, off, 64);
            }
            float m2 = s * (1.0f / DCC);
            float r2 = rsqrtf(q * (1.0f / DCC) - m2 * m2 + 1e-5f);
            short8 o;
            #pragma unroll
            for (int j = 0; j < 8; ++j)
                o[j] = (short)f2bf((tv[j] - m2) * r2 * gr[j] + br[j]);
            *(short8*)(outp + gbase) = o;
        }
    }
}

// ---------------------------------------------------------------------------
extern "C" void kernel_launch(void* const* d_in, const int* in_sizes, int n_in,
                              void* d_out, int out_size, void* d_ws, size_t ws_size,
                              hipStream_t stream)
{
    const float* qwen   = (const float*)d_in[0];
    const float* obs    = (const float*)d_in[1];
    const float* proj_W = (const float*)d_in[2];
    const float* proj_b = (const float*)d_in[3];
    const float* fuse_W = (const float*)d_in[4];
    const float* fuse_b = (const float*)d_in[5];
    const float* up_W   = (const float*)d_in[6];
    const float* up_b   = (const float*)d_in[7];
    const float* lat_W  = (const float*)d_in[8];
    const float* lat_b  = (const float*)d_in[9];
    const float* plogit = (const float*)d_in[10];
    const float* ln_g   = (const float*)d_in[11];
    const float* ln_b   = (const float*)d_in[12];
    const float* down_W = (const float*)d_in[13];
    const float* down_b = (const float*)d_in[14];
    const float* out1_W = (const float*)d_in[15];
    const float* out1_b = (const float*)d_in[16];
    const float* out2_W = (const float*)d_in[17];
    const float* out2_b = (const float*)d_in[18];
    float* out = (float*)d_out;

    // ---- ws layout (ushort); footprint 228.6 MB (proven)
    unsigned short* wsu = (unsigned short*)d_ws;
    float*          bp     = (float*)wsu;                  // 512 f32
    unsigned short* h16    = wsu + 2048;                   // head scratch
    unsigned short* M16    = wsu + 8388608;                // (4,512,2048)
    unsigned short* x0b    = wsu + 16777216;
    unsigned short* acts16[4] = {
        wsu + 20971520, wsu + 20971520 + TOKH,
        wsu + 20971520 + 2 * TOKH, wsu + 20971520 + 3 * TOKH };
    unsigned short* w16    = wsu + 37748736;
    unsigned short* fuseW16 = w16;
    unsigned short* upW16   = w16 + 1048576;
    unsigned short* latW16  = w16 + 2097152;
    unsigned short* downW16 = w16 + 3145728;
    unsigned short* out1W16 = w16 + 3932160;
    unsigned short* out2W16 = w16 + 4194304;
    unsigned short* projT16 = wsu + 47185920;              // (4,2048,512)
    unsigned short* obs16   = wsu + 47185920;              // overlays projT16

    // d_out overlays: part32 (front); pred a/b + lat0..3 (settle)
    float*          part32  = (float*)d_out;
    unsigned short* outu = (unsigned short*)d_out;
    unsigned short* pred16a = outu;
    unsigned short* pred16b = outu + TOKH;
    unsigned short* lat16[4] = { outu + 2*TOKH, outu + 3*TOKH, outu + 4*TOKH, outu + 5*TOKH };

    dim3 blk(256);
    dim3 blk512(512);

    {
        CvtArgs ca;
        ca.src[0] = fuse_W; ca.src[1] = up_W;   ca.src[2] = lat_W;
        ca.src[3] = down_W; ca.src[4] = out1_W; ca.src[5] = out2_W;
        wcvt_kernel<<<dim3(2048), blk, 0, stream>>>(ca, w16);
    }
    ptr_kernel<<<dim3(DMD/32, DCC/32, 4), blk, 0, stream>>>(proj_W, projT16);
    bprime_kernel<<<dim3(DCC/8), blk, 0, stream>>>(fuse_W, fuse_b, proj_b, bp);

    // ---- M_o = fuseW_o @ projW_o  (512x2048 each, K=512); consumes projT16
    {
        GArgs a{};
        for (int o = 0; o < 4; ++o) {
            a.A[o] = fuseW16 + o * DCC;
            a.W[o] = projT16 + (size_t)o * DMD * DCC;
            a.bias[o] = nullptr;
            a.C[o] = M16 + (size_t)o * DCC * DMD;
        }
        gemm16<false, false><<<dim3(DMD/128, DCC/128, 4), blk, 0, stream>>>(
            a, 4 * DCC, DCC, 0, DMD, DCC);
    }

    // ---- obs -> bf16 (one BW-bound pass; overwrites dead projT16 region)
    cvt_kernel<<<dim3(4096), blk, 0, stream>>>(obs, obs16, 16777216);

    // ---- x0 split-K partials: pure-bf16 gemm16, grid 1024 = ~4 blocks/CU
    {
        GArgs a{};
        for (int o = 0; o < 4; ++o) {
            a.A[o] = obs16 + (size_t)o * NTOK * DMD;
            a.W[o] = M16 + (size_t)o * DCC * DMD;
            a.bias[o] = nullptr;
            a.add[o]  = nullptr;
            a.C[o] = part32 + (size_t)o * TOKH;
        }
        gemm16<true, false><<<dim3(DCC/128, NTOK/128, 4), blk, 0, stream>>>(
            a, DMD, DMD, 0, DCC, DMD);
    }
    // ---- x0 = bf16(sum partials + b')
    x0red<<<dim3(TOKH/4/256), blk, 0, stream>>>(part32, bp, x0b);

    dim3 fgrid(NTOK / 16);   // 512 blocks -> 2 blocks/CU

    // ---- initial bottom-up pass
    for (int i = 0; i < 4; ++i) {
        gemm_fused<0><<<fgrid, blk512, 0, stream>>>(
            (i == 0) ? x0b : acts16[i - 1],
            upW16 + (size_t)i * DCC * DCC, up_b + i * DCC,
            ln_g + i * DCC, ln_b + i * DCC,
            nullptr, nullptr, nullptr, nullptr, acts16[i]);
    }

    // ---- settling iterations
    for (int s = 0; s < 5; ++s) {
        {
            GArgs a{};
            a.A[0] = acts16[1]; a.W[0] = downW16 + (size_t)1 * DCC * DCC;
            a.bias[0] = down_b + 1 * DCC; a.C[0] = pred16a;
            a.A[1] = acts16[2]; a.W[1] = downW16 + (size_t)2 * DCC * DCC;
            a.bias[1] = down_b + 2 * DCC; a.C[1] = pred16b;
            for (int i = 0; i < 4; ++i) {
                a.A[2 + i] = acts16[i];
                a.W[2 + i] = latW16 + (size_t)i * DCC * DCC;
                a.bias[2 + i] = lat_b + i * DCC;
                a.C[2 + i] = lat16[i];
            }
            gemm16<false, false><<<dim3(DCC/128, NTOK/128, 6), blk, 0, stream>>>(
                a, DCC, DCC, 0, DCC, DCC);
        }
        for (int i = 0; i < 4; ++i) {
            const unsigned short* tgt =
                (i == 0) ? pred16a : (i == 1) ? pred16b : acts16[i];
            gemm_fused<1><<<fgrid, blk512, 0, stream>>>(
                (i == 0) ? x0b : acts16[i - 1],
                upW16 + (size_t)i * DCC * DCC, up_b + i * DCC,
                ln_g + i * DCC, ln_b + i * DCC,
                acts16[i], tgt, lat16[i], plogit + i * DCC, acts16[i]);
        }
    }

    // ---- head
    {
        GArgs a{};
        a.A[0] = acts16[3]; a.W[0] = out1W16; a.bias[0] = out1_b; a.C[0] = h16;
        gemm16<false, true><<<dim3(DCC/128, NTOK/128, 1), blk, 0, stream>>>(
            a, DCC, DCC, 0, DCC, DCC);
    }
    {
        GArgs a{};
        a.A[0] = h16; a.W[0] = out2W16; a.bias[0] = out2_b;
        a.add[0] = qwen; a.C[0] = out;
        gemm16<true, false><<<dim3(DMD/128, NTOK/128, 1), blk, 0, stream>>>(
            a, DCC, DCC, DMD, DMD, DCC);
    }
}

// Round 13
// 1484.149 us; speedup vs baseline: 2.1670x; 1.0851x over previous
//
#include <hip/hip_runtime.h>
#include <hip/hip_bf16.h>
#include <math.h>

#define NTOK 8192     // B*S
#define DMD  2048     // d_model
#define DCC  512      // d_cortical
#define TOKH 4194304  // NTOK*DCC

typedef __attribute__((ext_vector_type(8))) short short8;
typedef __attribute__((ext_vector_type(4))) float f32x4;

// ---------------- helpers ---------------------------------------------------
__device__ inline float bf2f(unsigned short u) {
    union { unsigned int i; float f; } x; x.i = ((unsigned int)u) << 16; return x.f;
}
__device__ inline unsigned short f2bf(float f) {
    union { float f; unsigned int i; } x; x.f = f;
    unsigned int u = x.i;
    return (unsigned short)((u + 0x7fffu + ((u >> 16) & 1u)) >> 16);
}

typedef const __attribute__((address_space(1))) unsigned int* gas1_t;
typedef __attribute__((address_space(3))) unsigned int* las3_t;
__device__ inline void async16(const void* g, void* l) {
    __builtin_amdgcn_global_load_lds(
        (gas1_t)g,
        (las3_t)(unsigned int)(unsigned long long)l, 16, 0, 0);
}

#define VMCNT(N) asm volatile("s_waitcnt vmcnt(" #N ")" ::: "memory")

// ---------------- fp32 -> bf16 bulk conversion (grid-stride) ----------------
__global__ __launch_bounds__(256)
void cvt_kernel(const float* __restrict__ s, unsigned short* __restrict__ d, int n4)
{
    for (int i = blockIdx.x * 256 + threadIdx.x; i < n4; i += gridDim.x * 256) {
        float4 v = ((const float4*)s)[i];
        ushort4 o;
        o.x = f2bf(v.x); o.y = f2bf(v.y); o.z = f2bf(v.z); o.w = f2bf(v.w);
        ((ushort4*)d)[i] = o;
    }
}

// ---------------- merged fp32 -> bf16 weight conversion ---------------------
struct CvtArgs { const float* src[6]; };

__global__ __launch_bounds__(256)
void wcvt_kernel(CvtArgs ca, unsigned short* __restrict__ dst)
{
    const int total = 1310720;  // f4 units
    for (int i = blockIdx.x * 256 + threadIdx.x; i < total; i += gridDim.x * 256) {
        const float* sp; int base;
        if      (i <  262144) { sp = ca.src[0]; base = 0;       }  // fuse_W
        else if (i <  524288) { sp = ca.src[1]; base = 262144;  }  // up_W
        else if (i <  786432) { sp = ca.src[2]; base = 524288;  }  // lateral_W
        else if (i <  983040) { sp = ca.src[3]; base = 786432;  }  // down_W
        else if (i < 1048576) { sp = ca.src[4]; base = 983040;  }  // out1_W
        else                  { sp = ca.src[5]; base = 1048576; }  // out2_W
        float4 v = ((const float4*)sp)[i - base];
        ushort4 o;
        o.x = f2bf(v.x); o.y = f2bf(v.y); o.z = f2bf(v.z); o.w = f2bf(v.w);
        ((ushort4*)dst)[i] = o;
    }
}

// ---------------- proj_W transpose: (4,512,2048) f32 -> (4,2048,512) bf16 ---
__global__ __launch_bounds__(256)
void ptr_kernel(const float* __restrict__ src, unsigned short* __restrict__ dst)
{
    __shared__ float t[32][33];
    const int o  = blockIdx.z;
    const int jb = blockIdx.x * 32;
    const int kb = blockIdx.y * 32;
    const int r  = threadIdx.x >> 3;
    const int c4 = (threadIdx.x & 7) * 4;
    {
        const float* s = src + ((size_t)o * DCC + kb + r) * DMD + jb + c4;
        float4 v = *(const float4*)s;
        t[r][c4+0]=v.x; t[r][c4+1]=v.y; t[r][c4+2]=v.z; t[r][c4+3]=v.w;
    }
    __syncthreads();
    {
        ushort4 u;
        u.x = f2bf(t[c4+0][r]); u.y = f2bf(t[c4+1][r]);
        u.z = f2bf(t[c4+2][r]); u.w = f2bf(t[c4+3][r]);
        *(ushort4*)(dst + ((size_t)o * DMD + jb + r) * DCC + kb + c4) = u;
    }
}

// ---------------- b' = fuse_b + fuse_W @ proj_b_flat (exact f32) ------------
__global__ __launch_bounds__(256)
void bprime_kernel(const float* __restrict__ fuse_W, const float* __restrict__ fuse_b,
                   const float* __restrict__ proj_b, float* __restrict__ bp)
{
    const int row = blockIdx.x * 8 + (threadIdx.x >> 5);
    const int l32 = threadIdx.x & 31;
    const float* r = fuse_W + (size_t)row * (4 * DCC) + l32 * 64;
    const float* p = proj_b + l32 * 64;
    float s = 0.f;
    #pragma unroll
    for (int k = 0; k < 64; k += 4) {
        float4 v = *(const float4*)(r + k);
        float4 q = *(const float4*)(p + k);
        s += v.x*q.x + v.y*q.y + v.z*q.z + v.w*q.w;
    }
    #pragma unroll
    for (int off = 16; off; off >>= 1) s += __shfl_xor(s, off, 64);
    if (l32 == 0) bp[row] = s + fuse_b[row];
}

// ---------------- batched bf16 MFMA GEMM (m97 structure + XCD swizzle) ------
struct GArgs {
    const unsigned short* A[6];
    const unsigned short* W[6];
    const float*          bias[6];
    const float*          add[6];
    void*                 C[6];
};

template<bool OUTF32, bool GELU>
__global__ __launch_bounds__(256)
void gemm16(GArgs ga, int lda, int ldw, int ldadd, int ldc, int K)
{
    __shared__ unsigned short As[128 * 32];   // 8 KB
    __shared__ unsigned short Bs[128 * 32];   // 8 KB

    const int z    = blockIdx.z;
    const int tid  = threadIdx.x;
    const int wave = tid >> 6;
    const int lane = tid & 63;

    const int nwg   = gridDim.x * gridDim.y;
    const int bid   = blockIdx.y * gridDim.x + blockIdx.x;
    const int swz   = (bid & 7) * (nwg >> 3) + (bid >> 3);
    const int bn    = (swz % gridDim.x) * 128;
    const int bm    = (swz / gridDim.x) * 128;

    const int wr   = wave >> 1;
    const int wc   = wave & 1;

    const unsigned short* Ap = ga.A[z];
    const unsigned short* Wp = ga.W[z];

    const int lrow = lane >> 2;
    const int lcol = (lane & 3) * 8;

    f32x4 acc[4][4] = {};

    for (int k0 = 0; k0 < K; k0 += 32) {
        #pragma unroll
        for (int r = 0; r < 2; ++r) {
            int c = wave + r * 4;
            async16(Ap + (size_t)(bm + c * 16 + lrow) * lda + k0 + lcol, As + c * 512);
            async16(Wp + (size_t)(bn + c * 16 + lrow) * ldw + k0 + lcol, Bs + c * 512);
        }
        __syncthreads();

        short8 af[4], bfr[4];
        #pragma unroll
        for (int i = 0; i < 4; ++i) {
            af[i]  = *(const short8*)&As[(wr * 64 + i * 16 + (lane & 15)) * 32 + (lane >> 4) * 8];
            bfr[i] = *(const short8*)&Bs[(wc * 64 + i * 16 + (lane & 15)) * 32 + (lane >> 4) * 8];
        }
        #pragma unroll
        for (int mi = 0; mi < 4; ++mi)
            #pragma unroll
            for (int ni = 0; ni < 4; ++ni)
                acc[mi][ni] = __builtin_amdgcn_mfma_f32_16x16x32_bf16(
                    af[mi], bfr[ni], acc[mi][ni], 0, 0, 0);
        __syncthreads();
    }

    const float* bias = ga.bias[z];
    const float* add  = ga.add[z];
    #pragma unroll
    for (int ni = 0; ni < 4; ++ni) {
        int col = bn + wc * 64 + ni * 16 + (lane & 15);
        float bv = bias ? bias[col] : 0.0f;
        #pragma unroll
        for (int mi = 0; mi < 4; ++mi) {
            #pragma unroll
            for (int r = 0; r < 4; ++r) {
                int row = bm + wr * 64 + mi * 16 + (lane >> 4) * 4 + r;
                float vv = acc[mi][ni][r] + bv;
                if (GELU) vv = 0.5f * vv * (1.0f + erff(vv * 0.7071067811865475f));
                if (OUTF32) {
                    if (add) vv += add[(size_t)row * ldadd + col];
                    ((float*)ga.C[z])[(size_t)row * ldc + col] = vv;
                } else {
                    ((unsigned short*)ga.C[z])[(size_t)row * ldc + col] = f2bf(vv);
                }
            }
        }
    }
}

// ---------------- x0 reduce: x0 = bf16(sum_o partial_o + b') ----------------
__global__ __launch_bounds__(256)
void x0red(const float* __restrict__ partial, const float* __restrict__ bp,
           unsigned short* __restrict__ x0)
{
    const int i = blockIdx.x * 256 + threadIdx.x;   // f4 units, total 1048576
    float4 a = ((const float4*)partial)[i];
    float4 b = ((const float4*)(partial + TOKH))[i];
    float4 c = ((const float4*)(partial + 2 * (size_t)TOKH))[i];
    float4 d = ((const float4*)(partial + 3 * (size_t)TOKH))[i];
    const int col = (i * 4) & (DCC - 1);
    float4 bv = *(const float4*)(bp + col);
    ushort4 o;
    o.x = f2bf(a.x + b.x + c.x + d.x + bv.x);
    o.y = f2bf(a.y + b.y + c.y + d.y + bv.y);
    o.z = f2bf(a.z + b.z + c.z + d.z + bv.z);
    o.w = f2bf(a.w + b.w + c.w + d.w + bv.w);
    ((ushort4*)x0)[i] = o;
}

// ---------------- fused GEMM + LN (+update), counted-vmcnt pipeline ---------
// Block tile: 32 rows x 512 cols, K=512, 512 threads / 8 waves, grid 256
// (1 block/CU). K-loop: 3-deep LDS buffers, loads issued 2 steps ahead, raw
// s_barriers with COUNTED vmcnt (never 0 mid-loop) so W-loads stay in flight
// across barriers -- the __syncthreads vmcnt(0) drain was the exposed-latency
// bottleneck at 1 block/CU (T3/T4; m218 mechanism).
// Per step: waves 0-1 issue 5 loads (A+4B), waves 2-7 issue 4 (B only).
// LDS: Bs 3x32K + As3 3x2K + red 2K = 104 KB.
__device__ inline int csw(int rl, int col) {
    int s = ((rl >> 2) & 3) ^ (rl & 3);
    return rl * 512 + (col ^ (s << 4));
}

template<int MODE>
__global__ __launch_bounds__(512)
void gemm_fused(const unsigned short* __restrict__ Ap,
                const unsigned short* __restrict__ Wp,
                const float* __restrict__ bias,
                const float* __restrict__ g,
                const float* __restrict__ b,
                const unsigned short* a_in,
                const unsigned short* t_in,
                const unsigned short* __restrict__ lat_in,
                const float* __restrict__ logit,
                unsigned short* outp)
{
    __shared__ unsigned short Bs[3][512 * 32];   // 96 KB
    __shared__ unsigned short As3[3][32 * 32];   //  6 KB
    __shared__ float red[2][8][32];              //  2 KB

    const int tid  = threadIdx.x;
    const int wave = tid >> 6;         // 0..7
    const int lane = tid & 63;
    const int lrow = lane >> 2;        // 0..15
    const int lc8  = (lane & 3) * 8;   // 0,8,16,24
    const int bm   = blockIdx.x * 32;
    const int l15  = lane & 15;
    const int lh   = lane >> 4;
    const int c0   = lane * 8;

    f32x4 acc[2][4] = {};

    auto issue = [&](int buf, int k0) {
        if (wave < 2)
            async16(Ap + (size_t)(bm + wave * 16 + lrow) * DCC + k0 + lc8,
                    &As3[buf][wave * 512]);
        #pragma unroll
        for (int r = 0; r < 4; ++r)
            async16(Wp + (size_t)((r * 8 + wave) * 16 + lrow) * DCC + k0 + lc8,
                    &Bs[buf][(r * 8 + wave) * 512]);
    };

    // prologue: batches for steps 0 and 1
    issue(0, 0);
    issue(1, 32);

    #pragma unroll
    for (int t = 0; t < 16; ++t) {
        const int cur = t % 3;
        if (t + 2 < 16) issue((t + 2) % 3, (t + 2) * 32);
        // counted wait: own batch for buf[cur] complete (2/1/0 younger batches)
        if (t < 14)      { if (wave < 2) VMCNT(10); else VMCNT(8); }
        else if (t == 14){ if (wave < 2) VMCNT(5);  else VMCNT(4); }
        else             { VMCNT(0); }
        __builtin_amdgcn_s_barrier();   // publish buf[cur] to all waves
        short8 af[2], bfr[4];
        #pragma unroll
        for (int mi = 0; mi < 2; ++mi)
            af[mi] = *(const short8*)&As3[cur][(mi * 16 + l15) * 32 + lh * 8];
        #pragma unroll
        for (int ni = 0; ni < 4; ++ni)
            bfr[ni] = *(const short8*)&Bs[cur][(wave * 64 + ni * 16 + l15) * 32 + lh * 8];
        #pragma unroll
        for (int mi = 0; mi < 2; ++mi)
            #pragma unroll
            for (int ni = 0; ni < 4; ++ni)
                acc[mi][ni] = __builtin_amdgcn_mfma_f32_16x16x32_bf16(
                    af[mi], bfr[ni], acc[mi][ni], 0, 0, 0);
        __builtin_amdgcn_s_barrier();   // reads of buf[cur] done (next overwrite safe)
    }

    // ---- LN1 row stats in MFMA layout ----
    float bv[4], gv[4], bbv[4];
    #pragma unroll
    for (int ni = 0; ni < 4; ++ni) {
        int col = wave * 64 + ni * 16 + l15;
        bv[ni] = bias[col]; gv[ni] = g[col]; bbv[ni] = b[col];
    }

    float ps[2][4], pq[2][4];
    #pragma unroll
    for (int mi = 0; mi < 2; ++mi)
        #pragma unroll
        for (int rr = 0; rr < 4; ++rr) {
            float s = 0.f, q = 0.f;
            #pragma unroll
            for (int ni = 0; ni < 4; ++ni) {
                float v = acc[mi][ni][rr] + bv[ni];
                acc[mi][ni][rr] = v;
                s += v; q += v * v;
            }
            #pragma unroll
            for (int off = 1; off < 16; off <<= 1) {
                s += __shfl_xor(s, off, 64);
                q += __shfl_xor(q, off, 64);
            }
            ps[mi][rr] = s; pq[mi][rr] = q;
        }
    if (l15 == 0) {
        #pragma unroll
        for (int mi = 0; mi < 2; ++mi)
            #pragma unroll
            for (int rr = 0; rr < 4; ++rr) {
                int rl = mi * 16 + lh * 4 + rr;
                red[0][wave][rl] = ps[mi][rr];
                red[1][wave][rl] = pq[mi][rr];
            }
    }
    __syncthreads();

    // comp = LN1 result -> compS (reuse Bs[0]; K-loop fully done)
    unsigned short* compS = &Bs[0][0];
    #pragma unroll
    for (int mi = 0; mi < 2; ++mi)
        #pragma unroll
        for (int rr = 0; rr < 4; ++rr) {
            int rl = mi * 16 + lh * 4 + rr;
            float s = 0.f, q = 0.f;
            #pragma unroll
            for (int w = 0; w < 8; ++w) { s += red[0][w][rl]; q += red[1][w][rl]; }
            float m1 = s * (1.0f / DCC);
            float r1 = rsqrtf(q * (1.0f / DCC) - m1 * m1 + 1e-5f);
            #pragma unroll
            for (int ni = 0; ni < 4; ++ni) {
                int col = wave * 64 + ni * 16 + l15;
                compS[csw(rl, col)] = f2bf((acc[mi][ni][rr] - m1) * r1 * gv[ni] + bbv[ni]);
            }
        }
    __syncthreads();

    // ---- phase 2: row-mapped (wave owns 4 rows, lane owns 8 contiguous cols)
    if constexpr (MODE == 0) {
        #pragma unroll
        for (int rr = 0; rr < 4; ++rr) {
            const int rl = wave * 4 + rr;
            const size_t gbase = (size_t)(bm + rl) * DCC + c0;
            short8 cm = *(const short8*)&compS[csw(rl, c0)];
            *(short8*)(outp + gbase) = cm;
        }
    } else {
        float gr[8], br[8], pr[8];
        {
            float4 g0 = *(const float4*)(g + c0),     g1 = *(const float4*)(g + c0 + 4);
            float4 b0 = *(const float4*)(b + c0),     b1 = *(const float4*)(b + c0 + 4);
            float4 p0 = *(const float4*)(logit + c0), p1 = *(const float4*)(logit + c0 + 4);
            float gt[8] = {g0.x,g0.y,g0.z,g0.w,g1.x,g1.y,g1.z,g1.w};
            float bt[8] = {b0.x,b0.y,b0.z,b0.w,b1.x,b1.y,b1.z,b1.w};
            float pt[8] = {p0.x,p0.y,p0.z,p0.w,p1.x,p1.y,p1.z,p1.w};
            #pragma unroll
            for (int j = 0; j < 8; ++j) {
                gr[j] = gt[j]; br[j] = bt[j];
                pr[j] = 1.0f / (1.0f + __expf(-pt[j]));
            }
        }
        #pragma unroll
        for (int rr = 0; rr < 4; ++rr) {
            const int rl = wave * 4 + rr;
            const size_t gbase = (size_t)(bm + rl) * DCC + c0;
            short8 cm = *(const short8*)&compS[csw(rl, c0)];
            short8 ar = *(const short8*)(a_in + gbase);
            short8 tr = *(const short8*)(t_in + gbase);
            short8 lr = *(const short8*)(lat_in + gbase);
            float tv[8], s = 0.f, q = 0.f;
            #pragma unroll
            for (int j = 0; j < 8; ++j) {
                float val = bf2f((unsigned short)ar[j])
                          + 0.5f * (bf2f((unsigned short)cm[j]) - bf2f((unsigned short)tr[j])) * pr[j]
                          + 0.1f * bf2f((unsigned short)lr[j]);
                tv[j] = val; s += val; q += val * val;
            }
            #pragma unroll
            for (int off = 1; off < 64; off <<= 1) {
                s += __shfl_xor(s, off, 64);
                q += __shfl_xor(q, off, 64);
            }
            float m2 = s * (1.0f / DCC);
            float r2 = rsqrtf(q * (1.0f / DCC) - m2 * m2 + 1e-5f);
            short8 o;
            #pragma unroll
            for (int j = 0; j < 8; ++j)
                o[j] = (short)f2bf((tv[j] - m2) * r2 * gr[j] + br[j]);
            *(short8*)(outp + gbase) = o;
        }
    }
}

// ---------------------------------------------------------------------------
extern "C" void kernel_launch(void* const* d_in, const int* in_sizes, int n_in,
                              void* d_out, int out_size, void* d_ws, size_t ws_size,
                              hipStream_t stream)
{
    const float* qwen   = (const float*)d_in[0];
    const float* obs    = (const float*)d_in[1];
    const float* proj_W = (const float*)d_in[2];
    const float* proj_b = (const float*)d_in[3];
    const float* fuse_W = (const float*)d_in[4];
    const float* fuse_b = (const float*)d_in[5];
    const float* up_W   = (const float*)d_in[6];
    const float* up_b   = (const float*)d_in[7];
    const float* lat_W  = (const float*)d_in[8];
    const float* lat_b  = (const float*)d_in[9];
    const float* plogit = (const float*)d_in[10];
    const float* ln_g   = (const float*)d_in[11];
    const float* ln_b   = (const float*)d_in[12];
    const float* down_W = (const float*)d_in[13];
    const float* down_b = (const float*)d_in[14];
    const float* out1_W = (const float*)d_in[15];
    const float* out1_b = (const float*)d_in[16];
    const float* out2_W = (const float*)d_in[17];
    const float* out2_b = (const float*)d_in[18];
    float* out = (float*)d_out;

    // ---- ws layout (ushort); footprint 228.6 MB (proven)
    unsigned short* wsu = (unsigned short*)d_ws;
    float*          bp     = (float*)wsu;                  // 512 f32
    unsigned short* h16    = wsu + 2048;                   // head scratch
    unsigned short* M16    = wsu + 8388608;                // (4,512,2048)
    unsigned short* x0b    = wsu + 16777216;
    unsigned short* acts16[4] = {
        wsu + 20971520, wsu + 20971520 + TOKH,
        wsu + 20971520 + 2 * TOKH, wsu + 20971520 + 3 * TOKH };
    unsigned short* w16    = wsu + 37748736;
    unsigned short* fuseW16 = w16;
    unsigned short* upW16   = w16 + 1048576;
    unsigned short* latW16  = w16 + 2097152;
    unsigned short* downW16 = w16 + 3145728;
    unsigned short* out1W16 = w16 + 3932160;
    unsigned short* out2W16 = w16 + 4194304;
    unsigned short* projT16 = wsu + 47185920;              // (4,2048,512)
    unsigned short* obs16   = wsu + 47185920;              // overlays projT16

    // d_out overlays: part32 (front); pred a/b + lat0..3 (settle)
    float*          part32  = (float*)d_out;
    unsigned short* outu = (unsigned short*)d_out;
    unsigned short* pred16a = outu;
    unsigned short* pred16b = outu + TOKH;
    unsigned short* lat16[4] = { outu + 2*TOKH, outu + 3*TOKH, outu + 4*TOKH, outu + 5*TOKH };

    dim3 blk(256);
    dim3 blk512(512);

    {
        CvtArgs ca;
        ca.src[0] = fuse_W; ca.src[1] = up_W;   ca.src[2] = lat_W;
        ca.src[3] = down_W; ca.src[4] = out1_W; ca.src[5] = out2_W;
        wcvt_kernel<<<dim3(2048), blk, 0, stream>>>(ca, w16);
    }
    ptr_kernel<<<dim3(DMD/32, DCC/32, 4), blk, 0, stream>>>(proj_W, projT16);
    bprime_kernel<<<dim3(DCC/8), blk, 0, stream>>>(fuse_W, fuse_b, proj_b, bp);

    // ---- M_o = fuseW_o @ projW_o  (512x2048 each, K=512); consumes projT16
    {
        GArgs a{};
        for (int o = 0; o < 4; ++o) {
            a.A[o] = fuseW16 + o * DCC;
            a.W[o] = projT16 + (size_t)o * DMD * DCC;
            a.bias[o] = nullptr;
            a.C[o] = M16 + (size_t)o * DCC * DMD;
        }
        gemm16<false, false><<<dim3(DMD/128, DCC/128, 4), blk, 0, stream>>>(
            a, 4 * DCC, DCC, 0, DMD, DCC);
    }

    // ---- obs -> bf16 (one BW-bound pass; overwrites dead projT16 region)
    cvt_kernel<<<dim3(4096), blk, 0, stream>>>(obs, obs16, 16777216);

    // ---- x0 split-K partials: pure-bf16 gemm16, grid 1024 = ~4 blocks/CU
    {
        GArgs a{};
        for (int o = 0; o < 4; ++o) {
            a.A[o] = obs16 + (size_t)o * NTOK * DMD;
            a.W[o] = M16 + (size_t)o * DCC * DMD;
            a.bias[o] = nullptr;
            a.add[o]  = nullptr;
            a.C[o] = part32 + (size_t)o * TOKH;
        }
        gemm16<true, false><<<dim3(DCC/128, NTOK/128, 4), blk, 0, stream>>>(
            a, DMD, DMD, 0, DCC, DMD);
    }
    // ---- x0 = bf16(sum partials + b')
    x0red<<<dim3(TOKH/4/256), blk, 0, stream>>>(part32, bp, x0b);

    dim3 fgrid(NTOK / 32);   // 256 blocks = 1 block/CU

    // ---- initial bottom-up pass
    for (int i = 0; i < 4; ++i) {
        gemm_fused<0><<<fgrid, blk512, 0, stream>>>(
            (i == 0) ? x0b : acts16[i - 1],
            upW16 + (size_t)i * DCC * DCC, up_b + i * DCC,
            ln_g + i * DCC, ln_b + i * DCC,
            nullptr, nullptr, nullptr, nullptr, acts16[i]);
    }

    // ---- settling iterations
    for (int s = 0; s < 5; ++s) {
        {
            GArgs a{};
            a.A[0] = acts16[1]; a.W[0] = downW16 + (size_t)1 * DCC * DCC;
            a.bias[0] = down_b + 1 * DCC; a.C[0] = pred16a;
            a.A[1] = acts16[2]; a.W[1] = downW16 + (size_t)2 * DCC * DCC;
            a.bias[1] = down_b + 2 * DCC; a.C[1] = pred16b;
            for (int i = 0; i < 4; ++i) {
                a.A[2 + i] = acts16[i];
                a.W[2 + i] = latW16 + (size_t)i * DCC * DCC;
                a.bias[2 + i] = lat_b + i * DCC;
                a.C[2 + i] = lat16[i];
            }
            gemm16<false, false><<<dim3(DCC/128, NTOK/128, 6), blk, 0, stream>>>(
                a, DCC, DCC, 0, DCC, DCC);
        }
        for (int i = 0; i < 4; ++i) {
            const unsigned short* tgt =
                (i == 0) ? pred16a : (i == 1) ? pred16b : acts16[i];
            gemm_fused<1><<<fgrid, blk512, 0, stream>>>(
                (i == 0) ? x0b : acts16[i - 1],
                upW16 + (size_t)i * DCC * DCC, up_b + i * DCC,
                ln_g + i * DCC, ln_b + i * DCC,
                acts16[i], tgt, lat16[i], plogit + i * DCC, acts16[i]);
        }
    }

    // ---- head
    {
        GArgs a{};
        a.A[0] = acts16[3]; a.W[0] = out1W16; a.bias[0] = out1_b; a.C[0] = h16;
        gemm16<false, true><<<dim3(DCC/128, NTOK/128, 1), blk, 0, stream>>>(
            a, DCC, DCC, 0, DCC, DCC);
    }
    {
        GArgs a{};
        a.A[0] = h16; a.W[0] = out2W16; a.bias[0] = out2_b;
        a.add[0] = qwen; a.C[0] = out;
        gemm16<true, false><<<dim3(DMD/128, NTOK/128, 1), blk, 0, stream>>>(
            a, DCC, DCC, DMD, DMD, DCC);
    }
}

// Round 14
// 1407.279 us; speedup vs baseline: 2.2854x; 1.0546x over previous
//
#include <hip/hip_runtime.h>
#include <hip/hip_bf16.h>
#include <math.h>

#define NTOK 8192     // B*S
#define DMD  2048     // d_model
#define DCC  512      // d_cortical
#define TOKH 4194304  // NTOK*DCC

typedef __attribute__((ext_vector_type(8))) short short8;
typedef __attribute__((ext_vector_type(4))) float f32x4;

// ---------------- helpers ---------------------------------------------------
__device__ inline float bf2f(unsigned short u) {
    union { unsigned int i; float f; } x; x.i = ((unsigned int)u) << 16; return x.f;
}
__device__ inline unsigned short f2bf(float f) {
    union { float f; unsigned int i; } x; x.f = f;
    unsigned int u = x.i;
    return (unsigned short)((u + 0x7fffu + ((u >> 16) & 1u)) >> 16);
}

typedef const __attribute__((address_space(1))) unsigned int* gas1_t;
typedef __attribute__((address_space(3))) unsigned int* las3_t;
__device__ inline void async16(const void* g, void* l) {
    __builtin_amdgcn_global_load_lds(
        (gas1_t)g,
        (las3_t)(unsigned int)(unsigned long long)l, 16, 0, 0);
}

#define VMCNT(N) asm volatile("s_waitcnt vmcnt(" #N ")" ::: "memory")

// ---------------- fp32 -> bf16 bulk conversion (grid-stride) ----------------
__global__ __launch_bounds__(256)
void cvt_kernel(const float* __restrict__ s, unsigned short* __restrict__ d, int n4)
{
    for (int i = blockIdx.x * 256 + threadIdx.x; i < n4; i += gridDim.x * 256) {
        float4 v = ((const float4*)s)[i];
        ushort4 o;
        o.x = f2bf(v.x); o.y = f2bf(v.y); o.z = f2bf(v.z); o.w = f2bf(v.w);
        ((ushort4*)d)[i] = o;
    }
}

// ---------------- merged fp32 -> bf16 weight conversion ---------------------
struct CvtArgs { const float* src[6]; };

__global__ __launch_bounds__(256)
void wcvt_kernel(CvtArgs ca, unsigned short* __restrict__ dst)
{
    const int total = 1310720;  // f4 units
    for (int i = blockIdx.x * 256 + threadIdx.x; i < total; i += gridDim.x * 256) {
        const float* sp; int base;
        if      (i <  262144) { sp = ca.src[0]; base = 0;       }  // fuse_W
        else if (i <  524288) { sp = ca.src[1]; base = 262144;  }  // up_W
        else if (i <  786432) { sp = ca.src[2]; base = 524288;  }  // lateral_W
        else if (i <  983040) { sp = ca.src[3]; base = 786432;  }  // down_W
        else if (i < 1048576) { sp = ca.src[4]; base = 983040;  }  // out1_W
        else                  { sp = ca.src[5]; base = 1048576; }  // out2_W
        float4 v = ((const float4*)sp)[i - base];
        ushort4 o;
        o.x = f2bf(v.x); o.y = f2bf(v.y); o.z = f2bf(v.z); o.w = f2bf(v.w);
        ((ushort4*)dst)[i] = o;
    }
}

// ---------------- proj_W transpose: (4,512,2048) f32 -> (4,2048,512) bf16 ---
__global__ __launch_bounds__(256)
void ptr_kernel(const float* __restrict__ src, unsigned short* __restrict__ dst)
{
    __shared__ float t[32][33];
    const int o  = blockIdx.z;
    const int jb = blockIdx.x * 32;
    const int kb = blockIdx.y * 32;
    const int r  = threadIdx.x >> 3;
    const int c4 = (threadIdx.x & 7) * 4;
    {
        const float* s = src + ((size_t)o * DCC + kb + r) * DMD + jb + c4;
        float4 v = *(const float4*)s;
        t[r][c4+0]=v.x; t[r][c4+1]=v.y; t[r][c4+2]=v.z; t[r][c4+3]=v.w;
    }
    __syncthreads();
    {
        ushort4 u;
        u.x = f2bf(t[c4+0][r]); u.y = f2bf(t[c4+1][r]);
        u.z = f2bf(t[c4+2][r]); u.w = f2bf(t[c4+3][r]);
        *(ushort4*)(dst + ((size_t)o * DMD + jb + r) * DCC + kb + c4) = u;
    }
}

// ---------------- b' = fuse_b + fuse_W @ proj_b_flat (exact f32) ------------
__global__ __launch_bounds__(256)
void bprime_kernel(const float* __restrict__ fuse_W, const float* __restrict__ fuse_b,
                   const float* __restrict__ proj_b, float* __restrict__ bp)
{
    const int row = blockIdx.x * 8 + (threadIdx.x >> 5);
    const int l32 = threadIdx.x & 31;
    const float* r = fuse_W + (size_t)row * (4 * DCC) + l32 * 64;
    const float* p = proj_b + l32 * 64;
    float s = 0.f;
    #pragma unroll
    for (int k = 0; k < 64; k += 4) {
        float4 v = *(const float4*)(r + k);
        float4 q = *(const float4*)(p + k);
        s += v.x*q.x + v.y*q.y + v.z*q.z + v.w*q.w;
    }
    #pragma unroll
    for (int off = 16; off; off >>= 1) s += __shfl_xor(s, off, 64);
    if (l32 == 0) bp[row] = s + fuse_b[row];
}

// ---------------- batched bf16 MFMA GEMM (counted-vmcnt pipeline) -----------
// 128x128 tile, 4 waves, XCD swizzle. 3-deep LDS buffers; loads issued 2
// K-steps ahead; raw s_barriers with COUNTED vmcnt (4 loads/lane/batch ->
// waits 8/4/0) so W/A loads stay in flight across barriers (T3/T4, proven in
// R13's fused kernel). LDS 48 KB -> 3 blocks/CU (unchanged vs VGPR cap).
struct GArgs {
    const unsigned short* A[6];
    const unsigned short* W[6];
    const float*          bias[6];
    const float*          add[6];
    void*                 C[6];
};

template<bool OUTF32, bool GELU>
__global__ __launch_bounds__(256)
void gemm16(GArgs ga, int lda, int ldw, int ldadd, int ldc, int K)
{
    __shared__ unsigned short As[3][128 * 32];   // 24 KB
    __shared__ unsigned short Bs[3][128 * 32];   // 24 KB

    const int z    = blockIdx.z;
    const int tid  = threadIdx.x;
    const int wave = tid >> 6;
    const int lane = tid & 63;

    const int nwg   = gridDim.x * gridDim.y;
    const int bid   = blockIdx.y * gridDim.x + blockIdx.x;
    const int swz   = (bid & 7) * (nwg >> 3) + (bid >> 3);
    const int bn    = (swz % gridDim.x) * 128;
    const int bm    = (swz / gridDim.x) * 128;

    const int wr   = wave >> 1;
    const int wc   = wave & 1;

    const unsigned short* Ap = ga.A[z];
    const unsigned short* Wp = ga.W[z];

    const int lrow = lane >> 2;
    const int lcol = (lane & 3) * 8;
    const int l15  = lane & 15;
    const int lh   = lane >> 4;

    f32x4 acc[4][4] = {};

    const int nsteps = K >> 5;

    auto issue = [&](int buf, int k0) {
        #pragma unroll
        for (int r = 0; r < 2; ++r) {
            int c = wave + r * 4;
            async16(Ap + (size_t)(bm + c * 16 + lrow) * lda + k0 + lcol,
                    &As[buf][c * 512]);
            async16(Wp + (size_t)(bn + c * 16 + lrow) * ldw + k0 + lcol,
                    &Bs[buf][c * 512]);
        }
    };

    issue(0, 0);
    issue(1, 32);

    for (int t = 0; t < nsteps; ++t) {
        const int cur = t % 3;
        if (t + 2 < nsteps) issue((t + 2) % 3, (t + 2) * 32);
        const int rem = nsteps - 1 - t;   // younger batches possibly in flight
        if (rem >= 2)      VMCNT(8);
        else if (rem == 1) VMCNT(4);
        else               VMCNT(0);
        __builtin_amdgcn_s_barrier();     // publish buf[cur]

        short8 af[4], bfr[4];
        #pragma unroll
        for (int i = 0; i < 4; ++i) {
            af[i]  = *(const short8*)&As[cur][(wr * 64 + i * 16 + l15) * 32 + lh * 8];
            bfr[i] = *(const short8*)&Bs[cur][(wc * 64 + i * 16 + l15) * 32 + lh * 8];
        }
        __builtin_amdgcn_s_setprio(1);
        #pragma unroll
        for (int mi = 0; mi < 4; ++mi)
            #pragma unroll
            for (int ni = 0; ni < 4; ++ni)
                acc[mi][ni] = __builtin_amdgcn_mfma_f32_16x16x32_bf16(
                    af[mi], bfr[ni], acc[mi][ni], 0, 0, 0);
        __builtin_amdgcn_s_setprio(0);
        __builtin_amdgcn_s_barrier();     // buf[cur] reads done (safe to overwrite)
    }

    const float* bias = ga.bias[z];
    const float* add  = ga.add[z];
    #pragma unroll
    for (int ni = 0; ni < 4; ++ni) {
        int col = bn + wc * 64 + ni * 16 + l15;
        float bv = bias ? bias[col] : 0.0f;
        #pragma unroll
        for (int mi = 0; mi < 4; ++mi) {
            #pragma unroll
            for (int r = 0; r < 4; ++r) {
                int row = bm + wr * 64 + mi * 16 + lh * 4 + r;
                float vv = acc[mi][ni][r] + bv;
                if (GELU) vv = 0.5f * vv * (1.0f + erff(vv * 0.7071067811865475f));
                if (OUTF32) {
                    if (add) vv += add[(size_t)row * ldadd + col];
                    ((float*)ga.C[z])[(size_t)row * ldc + col] = vv;
                } else {
                    ((unsigned short*)ga.C[z])[(size_t)row * ldc + col] = f2bf(vv);
                }
            }
        }
    }
}

// ---------------- x0 reduce: x0 = bf16(sum_o partial_o + b') ----------------
__global__ __launch_bounds__(256)
void x0red(const float* __restrict__ partial, const float* __restrict__ bp,
           unsigned short* __restrict__ x0)
{
    const int i = blockIdx.x * 256 + threadIdx.x;   // f4 units, total 1048576
    float4 a = ((const float4*)partial)[i];
    float4 b = ((const float4*)(partial + TOKH))[i];
    float4 c = ((const float4*)(partial + 2 * (size_t)TOKH))[i];
    float4 d = ((const float4*)(partial + 3 * (size_t)TOKH))[i];
    const int col = (i * 4) & (DCC - 1);
    float4 bv = *(const float4*)(bp + col);
    ushort4 o;
    o.x = f2bf(a.x + b.x + c.x + d.x + bv.x);
    o.y = f2bf(a.y + b.y + c.y + d.y + bv.y);
    o.z = f2bf(a.z + b.z + c.z + d.z + bv.z);
    o.w = f2bf(a.w + b.w + c.w + d.w + bv.w);
    ((ushort4*)x0)[i] = o;
}

// ---------------- fused GEMM + LN (+update), counted-vmcnt pipeline ---------
// (R13 structure, + setprio around MFMA cluster.)
__device__ inline int csw(int rl, int col) {
    int s = ((rl >> 2) & 3) ^ (rl & 3);
    return rl * 512 + (col ^ (s << 4));
}

template<int MODE>
__global__ __launch_bounds__(512)
void gemm_fused(const unsigned short* __restrict__ Ap,
                const unsigned short* __restrict__ Wp,
                const float* __restrict__ bias,
                const float* __restrict__ g,
                const float* __restrict__ b,
                const unsigned short* a_in,
                const unsigned short* t_in,
                const unsigned short* __restrict__ lat_in,
                const float* __restrict__ logit,
                unsigned short* outp)
{
    __shared__ unsigned short Bs[3][512 * 32];   // 96 KB
    __shared__ unsigned short As3[3][32 * 32];   //  6 KB
    __shared__ float red[2][8][32];              //  2 KB

    const int tid  = threadIdx.x;
    const int wave = tid >> 6;         // 0..7
    const int lane = tid & 63;
    const int lrow = lane >> 2;        // 0..15
    const int lc8  = (lane & 3) * 8;   // 0,8,16,24
    const int bm   = blockIdx.x * 32;
    const int l15  = lane & 15;
    const int lh   = lane >> 4;
    const int c0   = lane * 8;

    f32x4 acc[2][4] = {};

    auto issue = [&](int buf, int k0) {
        if (wave < 2)
            async16(Ap + (size_t)(bm + wave * 16 + lrow) * DCC + k0 + lc8,
                    &As3[buf][wave * 512]);
        #pragma unroll
        for (int r = 0; r < 4; ++r)
            async16(Wp + (size_t)((r * 8 + wave) * 16 + lrow) * DCC + k0 + lc8,
                    &Bs[buf][(r * 8 + wave) * 512]);
    };

    issue(0, 0);
    issue(1, 32);

    #pragma unroll
    for (int t = 0; t < 16; ++t) {
        const int cur = t % 3;
        if (t + 2 < 16) issue((t + 2) % 3, (t + 2) * 32);
        if (t < 14)      { if (wave < 2) VMCNT(10); else VMCNT(8); }
        else if (t == 14){ if (wave < 2) VMCNT(5);  else VMCNT(4); }
        else             { VMCNT(0); }
        __builtin_amdgcn_s_barrier();   // publish buf[cur]
        short8 af[2], bfr[4];
        #pragma unroll
        for (int mi = 0; mi < 2; ++mi)
            af[mi] = *(const short8*)&As3[cur][(mi * 16 + l15) * 32 + lh * 8];
        #pragma unroll
        for (int ni = 0; ni < 4; ++ni)
            bfr[ni] = *(const short8*)&Bs[cur][(wave * 64 + ni * 16 + l15) * 32 + lh * 8];
        __builtin_amdgcn_s_setprio(1);
        #pragma unroll
        for (int mi = 0; mi < 2; ++mi)
            #pragma unroll
            for (int ni = 0; ni < 4; ++ni)
                acc[mi][ni] = __builtin_amdgcn_mfma_f32_16x16x32_bf16(
                    af[mi], bfr[ni], acc[mi][ni], 0, 0, 0);
        __builtin_amdgcn_s_setprio(0);
        __builtin_amdgcn_s_barrier();   // reads of buf[cur] done
    }

    // ---- LN1 row stats in MFMA layout ----
    float bv[4], gv[4], bbv[4];
    #pragma unroll
    for (int ni = 0; ni < 4; ++ni) {
        int col = wave * 64 + ni * 16 + l15;
        bv[ni] = bias[col]; gv[ni] = g[col]; bbv[ni] = b[col];
    }

    float ps[2][4], pq[2][4];
    #pragma unroll
    for (int mi = 0; mi < 2; ++mi)
        #pragma unroll
        for (int rr = 0; rr < 4; ++rr) {
            float s = 0.f, q = 0.f;
            #pragma unroll
            for (int ni = 0; ni < 4; ++ni) {
                float v = acc[mi][ni][rr] + bv[ni];
                acc[mi][ni][rr] = v;
                s += v; q += v * v;
            }
            #pragma unroll
            for (int off = 1; off < 16; off <<= 1) {
                s += __shfl_xor(s, off, 64);
                q += __shfl_xor(q, off, 64);
            }
            ps[mi][rr] = s; pq[mi][rr] = q;
        }
    if (l15 == 0) {
        #pragma unroll
        for (int mi = 0; mi < 2; ++mi)
            #pragma unroll
            for (int rr = 0; rr < 4; ++rr) {
                int rl = mi * 16 + lh * 4 + rr;
                red[0][wave][rl] = ps[mi][rr];
                red[1][wave][rl] = pq[mi][rr];
            }
    }
    __syncthreads();

    // comp = LN1 result -> compS (reuse Bs[0]; K-loop fully done)
    unsigned short* compS = &Bs[0][0];
    #pragma unroll
    for (int mi = 0; mi < 2; ++mi)
        #pragma unroll
        for (int rr = 0; rr < 4; ++rr) {
            int rl = mi * 16 + lh * 4 + rr;
            float s = 0.f, q = 0.f;
            #pragma unroll
            for (int w = 0; w < 8; ++w) { s += red[0][w][rl]; q += red[1][w][rl]; }
            float m1 = s * (1.0f / DCC);
            float r1 = rsqrtf(q * (1.0f / DCC) - m1 * m1 + 1e-5f);
            #pragma unroll
            for (int ni = 0; ni < 4; ++ni) {
                int col = wave * 64 + ni * 16 + l15;
                compS[csw(rl, col)] = f2bf((acc[mi][ni][rr] - m1) * r1 * gv[ni] + bbv[ni]);
            }
        }
    __syncthreads();

    // ---- phase 2: row-mapped (wave owns 4 rows, lane owns 8 contiguous cols)
    if constexpr (MODE == 0) {
        #pragma unroll
        for (int rr = 0; rr < 4; ++rr) {
            const int rl = wave * 4 + rr;
            const size_t gbase = (size_t)(bm + rl) * DCC + c0;
            short8 cm = *(const short8*)&compS[csw(rl, c0)];
            *(short8*)(outp + gbase) = cm;
        }
    } else {
        float gr[8], br[8], pr[8];
        {
            float4 g0 = *(const float4*)(g + c0),     g1 = *(const float4*)(g + c0 + 4);
            float4 b0 = *(const float4*)(b + c0),     b1 = *(const float4*)(b + c0 + 4);
            float4 p0 = *(const float4*)(logit + c0), p1 = *(const float4*)(logit + c0 + 4);
            float gt[8] = {g0.x,g0.y,g0.z,g0.w,g1.x,g1.y,g1.z,g1.w};
            float bt[8] = {b0.x,b0.y,b0.z,b0.w,b1.x,b1.y,b1.z,b1.w};
            float pt[8] = {p0.x,p0.y,p0.z,p0.w,p1.x,p1.y,p1.z,p1.w};
            #pragma unroll
            for (int j = 0; j < 8; ++j) {
                gr[j] = gt[j]; br[j] = bt[j];
                pr[j] = 1.0f / (1.0f + __expf(-pt[j]));
            }
        }
        #pragma unroll
        for (int rr = 0; rr < 4; ++rr) {
            const int rl = wave * 4 + rr;
            const size_t gbase = (size_t)(bm + rl) * DCC + c0;
            short8 cm = *(const short8*)&compS[csw(rl, c0)];
            short8 ar = *(const short8*)(a_in + gbase);
            short8 tr = *(const short8*)(t_in + gbase);
            short8 lr = *(const short8*)(lat_in + gbase);
            float tv[8], s = 0.f, q = 0.f;
            #pragma unroll
            for (int j = 0; j < 8; ++j) {
                float val = bf2f((unsigned short)ar[j])
                          + 0.5f * (bf2f((unsigned short)cm[j]) - bf2f((unsigned short)tr[j])) * pr[j]
                          + 0.1f * bf2f((unsigned short)lr[j]);
                tv[j] = val; s += val; q += val * val;
            }
            #pragma unroll
            for (int off = 1; off < 64; off <<= 1) {
                s += __shfl_xor(s, off, 64);
                q += __shfl_xor(q, off, 64);
            }
            float m2 = s * (1.0f / DCC);
            float r2 = rsqrtf(q * (1.0f / DCC) - m2 * m2 + 1e-5f);
            short8 o;
            #pragma unroll
            for (int j = 0; j < 8; ++j)
                o[j] = (short)f2bf((tv[j] - m2) * r2 * gr[j] + br[j]);
            *(short8*)(outp + gbase) = o;
        }
    }
}

// ---------------------------------------------------------------------------
extern "C" void kernel_launch(void* const* d_in, const int* in_sizes, int n_in,
                              void* d_out, int out_size, void* d_ws, size_t ws_size,
                              hipStream_t stream)
{
    const float* qwen   = (const float*)d_in[0];
    const float* obs    = (const float*)d_in[1];
    const float* proj_W = (const float*)d_in[2];
    const float* proj_b = (const float*)d_in[3];
    const float* fuse_W = (const float*)d_in[4];
    const float* fuse_b = (const float*)d_in[5];
    const float* up_W   = (const float*)d_in[6];
    const float* up_b   = (const float*)d_in[7];
    const float* lat_W  = (const float*)d_in[8];
    const float* lat_b  = (const float*)d_in[9];
    const float* plogit = (const float*)d_in[10];
    const float* ln_g   = (const float*)d_in[11];
    const float* ln_b   = (const float*)d_in[12];
    const float* down_W = (const float*)d_in[13];
    const float* down_b = (const float*)d_in[14];
    const float* out1_W = (const float*)d_in[15];
    const float* out1_b = (const float*)d_in[16];
    const float* out2_W = (const float*)d_in[17];
    const float* out2_b = (const float*)d_in[18];
    float* out = (float*)d_out;

    // ---- ws layout (ushort); footprint 228.6 MB (proven)
    unsigned short* wsu = (unsigned short*)d_ws;
    float*          bp     = (float*)wsu;                  // 512 f32
    unsigned short* h16    = wsu + 2048;                   // head scratch
    unsigned short* M16    = wsu + 8388608;                // (4,512,2048)
    unsigned short* x0b    = wsu + 16777216;
    unsigned short* acts16[4] = {
        wsu + 20971520, wsu + 20971520 + TOKH,
        wsu + 20971520 + 2 * TOKH, wsu + 20971520 + 3 * TOKH };
    unsigned short* w16    = wsu + 37748736;
    unsigned short* fuseW16 = w16;
    unsigned short* upW16   = w16 + 1048576;
    unsigned short* latW16  = w16 + 2097152;
    unsigned short* downW16 = w16 + 3145728;
    unsigned short* out1W16 = w16 + 3932160;
    unsigned short* out2W16 = w16 + 4194304;
    unsigned short* projT16 = wsu + 47185920;              // (4,2048,512)
    unsigned short* obs16   = wsu + 47185920;              // overlays projT16

    // d_out overlays: part32 (front); pred a/b + lat0..3 (settle)
    float*          part32  = (float*)d_out;
    unsigned short* outu = (unsigned short*)d_out;
    unsigned short* pred16a = outu;
    unsigned short* pred16b = outu + TOKH;
    unsigned short* lat16[4] = { outu + 2*TOKH, outu + 3*TOKH, outu + 4*TOKH, outu + 5*TOKH };

    dim3 blk(256);
    dim3 blk512(512);

    {
        CvtArgs ca;
        ca.src[0] = fuse_W; ca.src[1] = up_W;   ca.src[2] = lat_W;
        ca.src[3] = down_W; ca.src[4] = out1_W; ca.src[5] = out2_W;
        wcvt_kernel<<<dim3(2048), blk, 0, stream>>>(ca, w16);
    }
    ptr_kernel<<<dim3(DMD/32, DCC/32, 4), blk, 0, stream>>>(proj_W, projT16);
    bprime_kernel<<<dim3(DCC/8), blk, 0, stream>>>(fuse_W, fuse_b, proj_b, bp);

    // ---- M_o = fuseW_o @ projW_o  (512x2048 each, K=512); consumes projT16
    {
        GArgs a{};
        for (int o = 0; o < 4; ++o) {
            a.A[o] = fuseW16 + o * DCC;
            a.W[o] = projT16 + (size_t)o * DMD * DCC;
            a.bias[o] = nullptr;
            a.C[o] = M16 + (size_t)o * DCC * DMD;
        }
        gemm16<false, false><<<dim3(DMD/128, DCC/128, 4), blk, 0, stream>>>(
            a, 4 * DCC, DCC, 0, DMD, DCC);
    }

    // ---- obs -> bf16 (one BW-bound pass; overwrites dead projT16 region)
    cvt_kernel<<<dim3(4096), blk, 0, stream>>>(obs, obs16, 16777216);

    // ---- x0 split-K partials: pure-bf16 gemm16, grid 1024 = ~3-4 blocks/CU
    {
        GArgs a{};
        for (int o = 0; o < 4; ++o) {
            a.A[o] = obs16 + (size_t)o * NTOK * DMD;
            a.W[o] = M16 + (size_t)o * DCC * DMD;
            a.bias[o] = nullptr;
            a.add[o]  = nullptr;
            a.C[o] = part32 + (size_t)o * TOKH;
        }
        gemm16<true, false><<<dim3(DCC/128, NTOK/128, 4), blk, 0, stream>>>(
            a, DMD, DMD, 0, DCC, DMD);
    }
    // ---- x0 = bf16(sum partials + b')
    x0red<<<dim3(TOKH/4/256), blk, 0, stream>>>(part32, bp, x0b);

    dim3 fgrid(NTOK / 32);   // 256 blocks = 1 block/CU

    // ---- initial bottom-up pass
    for (int i = 0; i < 4; ++i) {
        gemm_fused<0><<<fgrid, blk512, 0, stream>>>(
            (i == 0) ? x0b : acts16[i - 1],
            upW16 + (size_t)i * DCC * DCC, up_b + i * DCC,
            ln_g + i * DCC, ln_b + i * DCC,
            nullptr, nullptr, nullptr, nullptr, acts16[i]);
    }

    // ---- settling iterations
    for (int s = 0; s < 5; ++s) {
        {
            GArgs a{};
            a.A[0] = acts16[1]; a.W[0] = downW16 + (size_t)1 * DCC * DCC;
            a.bias[0] = down_b + 1 * DCC; a.C[0] = pred16a;
            a.A[1] = acts16[2]; a.W[1] = downW16 + (size_t)2 * DCC * DCC;
            a.bias[1] = down_b + 2 * DCC; a.C[1] = pred16b;
            for (int i = 0; i < 4; ++i) {
                a.A[2 + i] = acts16[i];
                a.W[2 + i] = latW16 + (size_t)i * DCC * DCC;
                a.bias[2 + i] = lat_b + i * DCC;
                a.C[2 + i] = lat16[i];
            }
            gemm16<false, false><<<dim3(DCC/128, NTOK/128, 6), blk, 0, stream>>>(
                a, DCC, DCC, 0, DCC, DCC);
        }
        for (int i = 0; i < 4; ++i) {
            const unsigned short* tgt =
                (i == 0) ? pred16a : (i == 1) ? pred16b : acts16[i];
            gemm_fused<1><<<fgrid, blk512, 0, stream>>>(
                (i == 0) ? x0b : acts16[i - 1],
                upW16 + (size_t)i * DCC * DCC, up_b + i * DCC,
                ln_g + i * DCC, ln_b + i * DCC,
                acts16[i], tgt, lat16[i], plogit + i * DCC, acts16[i]);
        }
    }

    // ---- head
    {
        GArgs a{};
        a.A[0] = acts16[3]; a.W[0] = out1W16; a.bias[0] = out1_b; a.C[0] = h16;
        gemm16<false, true><<<dim3(DCC/128, NTOK/128, 1), blk, 0, stream>>>(
            a, DCC, DCC, 0, DCC, DCC);
    }
    {
        GArgs a{};
        a.A[0] = h16; a.W[0] = out2W16; a.bias[0] = out2_b;
        a.add[0] = qwen; a.C[0] = out;
        gemm16<true, false><<<dim3(DMD/128, NTOK/128, 1), blk, 0, stream>>>(
            a, DCC, DCC, DMD, DMD, DCC);
    }
}